// Round 1
// baseline (2655.627 us; speedup 1.0000x reference)
//
#include <hip/hip_runtime.h>
#include <hip/hip_bf16.h>
#include <math.h>

typedef __bf16 bf16_t;
typedef __attribute__((ext_vector_type(8))) __bf16 bf16x8;
typedef __attribute__((ext_vector_type(4))) float f32x4;

#define GAS __attribute__((address_space(1)))
#define LAS __attribute__((address_space(3)))

#define BB 2
#define TT 1024
#define CC 2048
#define HH 6
#define KK 128
#define VV 256
#define KD 768
#define VD 1536
#define NCAT 4608   // 768+768+1536+1536

__device__ __forceinline__ void gload_lds16(const void* g, void* l) {
  __builtin_amdgcn_global_load_lds((const GAS void*)g, (LAS void*)l, 16, 0, 0);
}

// ---------- f32 -> bf16 convert ----------
__global__ void k_cvt_bf16(const float* __restrict__ in, bf16_t* __restrict__ out, int n) {
  int i = (blockIdx.x * blockDim.x + threadIdx.x) * 4;
  if (i + 3 < n) {
    float4 v = *(const float4*)(in + i);
    out[i + 0] = (bf16_t)v.x;
    out[i + 1] = (bf16_t)v.y;
    out[i + 2] = (bf16_t)v.z;
    out[i + 3] = (bf16_t)v.w;
  }
}

// ---------- transpose [Kd,Nd] f32 -> [Nd,Kd] bf16 ----------
__global__ void k_transpose_cvt(const float* __restrict__ in, bf16_t* __restrict__ out,
                                int Kd, int Nd) {
  __shared__ float t[32][33];
  int n0 = blockIdx.x * 32, k0 = blockIdx.y * 32;
  int tx = threadIdx.x, ty = threadIdx.y;
#pragma unroll
  for (int i = 0; i < 32; i += 8)
    t[ty + i][tx] = in[(size_t)(k0 + ty + i) * Nd + n0 + tx];
  __syncthreads();
#pragma unroll
  for (int i = 0; i < 32; i += 8)
    out[(size_t)(n0 + ty + i) * Kd + k0 + tx] = (bf16_t)t[tx][ty + i];
}

// ---------- bf16 MFMA GEMM: C[M,N] = A[M,K] * B^T (B is [N,K]) ----------
__global__ __launch_bounds__(256, 2)
void k_gemm_bt(const bf16_t* __restrict__ A, const bf16_t* __restrict__ B,
               float* __restrict__ C, int M, int N, int K) {
  __shared__ __align__(16) bf16_t As[128 * 32];
  __shared__ __align__(16) bf16_t Bs[128 * 32];
  int tid = threadIdx.x;
  int wave = tid >> 6, lane = tid & 63;
  int wm = wave >> 1, wn = wave & 1;
  int by = blockIdx.y, bx = blockIdx.x;
  const bf16_t* Abase = A + (size_t)by * 128 * K;
  const bf16_t* Bbase = B + (size_t)bx * 128 * K;
  int kc = tid & 3;

  f32x4 acc[4][4];
#pragma unroll
  for (int i = 0; i < 4; ++i)
#pragma unroll
    for (int j = 0; j < 4; ++j) acc[i][j] = (f32x4){0.f, 0.f, 0.f, 0.f};

  for (int k0 = 0; k0 < K; k0 += 32) {
#pragma unroll
    for (int r = 0; r < 2; ++r) {
      int rowe = r * 64 + (tid >> 2);
      const bf16_t* ga = Abase + (size_t)rowe * K + k0 + kc * 8;
      const bf16_t* gb = Bbase + (size_t)rowe * K + k0 + kc * 8;
      gload_lds16(ga, As + (size_t)(r * 256 + wave * 64) * 8);
      gload_lds16(gb, Bs + (size_t)(r * 256 + wave * 64) * 8);
    }
    __syncthreads();
    int kg = lane >> 4, lr = lane & 15;
    bf16x8 af[4], bfv[4];
#pragma unroll
    for (int i = 0; i < 4; ++i) {
      af[i]  = *(const bf16x8*)(As + ((wm * 64 + i * 16 + lr) * 32 + kg * 8));
      bfv[i] = *(const bf16x8*)(Bs + ((wn * 64 + i * 16 + lr) * 32 + kg * 8));
    }
#pragma unroll
    for (int i = 0; i < 4; ++i)
#pragma unroll
      for (int j = 0; j < 4; ++j)
        acc[i][j] = __builtin_amdgcn_mfma_f32_16x16x32_bf16(af[i], bfv[j], acc[i][j], 0, 0, 0);
    __syncthreads();
  }

#pragma unroll
  for (int i = 0; i < 4; ++i) {
    int r0 = by * 128 + wm * 64 + i * 16 + ((lane >> 4) << 2);
#pragma unroll
    for (int j = 0; j < 4; ++j) {
      int c = bx * 128 + wn * 64 + j * 16 + (lane & 15);
      float* Cp = C + (size_t)r0 * N + c;
#pragma unroll
      for (int q = 0; q < 4; ++q) Cp[(size_t)q * N] = acc[i][j][q];
    }
  }
}

// ---------- beta / g (small N=6 GEMMs + activations) ----------
__global__ __launch_bounds__(64)
void k_ab(const float* __restrict__ hidden, const float* __restrict__ Wa,
          const float* __restrict__ Wb, const float* __restrict__ A_log,
          const float* __restrict__ dt_bias, float* __restrict__ g_out,
          float* __restrict__ beta_out) {
  int row = blockIdx.x;
  int lane = threadIdx.x;
  float accA[6] = {0, 0, 0, 0, 0, 0};
  float accB[6] = {0, 0, 0, 0, 0, 0};
  const float* h = hidden + (size_t)row * CC;
  for (int c = lane; c < CC; c += 64) {
    float x = h[c];
    const float* wa = Wa + c * 6;
    const float* wb = Wb + c * 6;
#pragma unroll
    for (int j = 0; j < 6; ++j) {
      accA[j] += x * wa[j];
      accB[j] += x * wb[j];
    }
  }
#pragma unroll
  for (int j = 0; j < 6; ++j) {
    for (int off = 32; off; off >>= 1) {
      accA[j] += __shfl_down(accA[j], off);
      accB[j] += __shfl_down(accB[j], off);
    }
  }
  if (lane == 0) {
#pragma unroll
    for (int j = 0; j < 6; ++j) {
      float a = accA[j] + dt_bias[j];
      float sp = (a > 20.f) ? a : log1pf(expf(a));
      g_out[(size_t)row * 6 + j] = -expf(A_log[j]) * sp;
      beta_out[(size_t)row * 6 + j] = 1.f / (1.f + expf(-accB[j]));
    }
  }
}

// ---------- depthwise causal conv(4) + SiLU (+ optional L2 norm over blockDim) ----------
__global__ void k_conv_silu(const float* __restrict__ pre, int ldpre, int col0,
                            const float* __restrict__ w, float* __restrict__ out,
                            int ld_out, int do_norm) {
  int row = blockIdx.x;     // b*T + t
  int t = row & (TT - 1);
  int h = blockIdx.y;
  int kk = threadIdx.x;
  int perH = blockDim.x;
  int ch = h * perH + kk;
  const float* wp = w + ch * 4;
  float y = 0.f;
#pragma unroll
  for (int i = 0; i < 4; ++i) {
    int tt = t - 3 + i;
    if (tt >= 0) y += wp[i] * pre[(size_t)(row - 3 + i) * ldpre + col0 + ch];
  }
  float s = y / (1.f + expf(-y));   // silu
  if (do_norm) {
    float ss = s * s;
#pragma unroll
    for (int off = 32; off; off >>= 1) ss += __shfl_down(ss, off);
    __shared__ float red[2];
    if ((threadIdx.x & 63) == 0) red[threadIdx.x >> 6] = ss;
    __syncthreads();
    float nrm = sqrtf(red[0] + red[1]);
    s = s / (nrm + 1e-6f);
  }
  out[(size_t)row * ld_out + ch] = s;
}

// ---------- sequential gated delta-rule scan ----------
// 12 blocks (b,h); 256 threads = one v-column each; state[128] in VGPRs.
__global__ __launch_bounds__(256, 1)
void k_scan(const float* __restrict__ q, const float* __restrict__ k,
            const float* __restrict__ v, const float* __restrict__ beta,
            const float* __restrict__ g, float* __restrict__ out) {
  int b = blockIdx.x / HH;
  int h = blockIdx.x % HH;
  int vi = threadIdx.x;
  float st[KK];
#pragma unroll
  for (int i = 0; i < KK; ++i) st[i] = 0.f;
  __shared__ float kq[2 * KK];
  __shared__ float sc[2];
  const float* qb = q + (size_t)b * TT * KD + h * KK;
  const float* kb = k + (size_t)b * TT * KD + h * KK;
  const float* vb = v + (size_t)b * TT * VD + h * VV;
  const float* gb = g + (size_t)b * TT * HH + h;
  const float* bb = beta + (size_t)b * TT * HH + h;
  float* ob = out + (size_t)b * TT * VD + h * VV;

  for (int t = 0; t < TT; ++t) {
    if (vi < KK) {
      kq[vi] = kb[(size_t)t * KD + vi];
      kq[KK + vi] = qb[(size_t)t * KD + vi];
    }
    if (vi == 0) {
      sc[0] = expf(gb[(size_t)t * HH]);
      sc[1] = bb[(size_t)t * HH];
    }
    float vt = vb[(size_t)t * VD + vi];
    __syncthreads();
    float eg = sc[0], be = sc[1];
    float kv = 0.f;
#pragma unroll
    for (int i = 0; i < KK; ++i) kv += st[i] * kq[i];
    float dv = be * (vt - eg * kv);
    float o = 0.f;
#pragma unroll
    for (int i = 0; i < KK; ++i) {
      st[i] = st[i] * eg + kq[i] * dv;
      o += kq[KK + i] * st[i];
    }
    ob[(size_t)t * VD + vi] = o;
    __syncthreads();
  }
}

// ---------- gated RMSNorm + output cast to bf16 ----------
__global__ __launch_bounds__(256)
void k_gatenorm(const float* __restrict__ attn, const float* __restrict__ fpre,
                const float* __restrict__ onorm_w, bf16_t* __restrict__ out) {
  int row = blockIdx.x;   // b*T + t
  int h = blockIdx.y;
  int vi = threadIdx.x;
  float x = attn[(size_t)row * VD + h * VV + vi];
  float ss = x * x;
#pragma unroll
  for (int off = 32; off; off >>= 1) ss += __shfl_down(ss, off);
  __shared__ float red[4];
  if ((threadIdx.x & 63) == 0) red[threadIdx.x >> 6] = ss;
  __syncthreads();
  float tot = red[0] + red[1] + red[2] + red[3];
  float r = rsqrtf(tot / (float)VV + 1e-5f);
  float gate = fpre[(size_t)row * NCAT + 3072 + h * VV + vi];
  float y = x * r * onorm_w[vi] * (gate / (1.f + expf(-gate)));
  out[(size_t)row * VD + h * VV + vi] = (bf16_t)y;
}

extern "C" void kernel_launch(void* const* d_in, const int* in_sizes, int n_in,
                              void* d_out, int out_size, void* d_ws, size_t ws_size,
                              hipStream_t stream) {
  const float* hidden = (const float*)d_in[0];
  const float* Wq = (const float*)d_in[1];
  const float* Wk = (const float*)d_in[2];
  const float* Wv = (const float*)d_in[3];
  const float* Wa = (const float*)d_in[4];
  const float* Wb = (const float*)d_in[5];
  const float* A_log = (const float*)d_in[6];
  const float* dt_bias = (const float*)d_in[7];
  const float* qconv = (const float*)d_in[8];
  const float* kconv = (const float*)d_in[9];
  const float* vconv = (const float*)d_in[10];
  const float* Wg = (const float*)d_in[11];
  const float* onorm = (const float*)d_in[12];
  const float* Wo = (const float*)d_in[13];
  float* out = (float*)d_out;

  char* ws = (char*)d_ws;
  size_t off = 0;
  auto alloc = [&](size_t bytes) {
    void* p = ws + off;
    off += (bytes + 255) & ~(size_t)255;
    return p;
  };
  const int M = BB * TT;  // 2048
  bf16_t* hbf   = (bf16_t*)alloc((size_t)M * CC * 2);
  bf16_t* WcatT = (bf16_t*)alloc((size_t)NCAT * CC * 2);
  bf16_t* WoT   = (bf16_t*)alloc((size_t)CC * VD * 2);
  float*  fpre  = (float*) alloc((size_t)M * NCAT * 4);
  float*  qn    = (float*) alloc((size_t)M * KD * 4);
  float*  kn    = (float*) alloc((size_t)M * KD * 4);
  float*  vn    = (float*) alloc((size_t)M * VD * 4);
  float*  gdec  = (float*) alloc((size_t)M * HH * 4);
  float*  beta  = (float*) alloc((size_t)M * HH * 4);
  float*  attn  = (float*) alloc((size_t)M * VD * 4);
  bf16_t* ovd   = (bf16_t*)alloc((size_t)M * VD * 2);

  // pre-pass: convert hidden, transpose+convert weights
  k_cvt_bf16<<<(M * CC / 4 + 255) / 256, 256, 0, stream>>>(hidden, hbf, M * CC);
  k_transpose_cvt<<<dim3(KD / 32, CC / 32), dim3(32, 8), 0, stream>>>(Wq, WcatT, CC, KD);
  k_transpose_cvt<<<dim3(KD / 32, CC / 32), dim3(32, 8), 0, stream>>>(Wk, WcatT + (size_t)768 * CC, CC, KD);
  k_transpose_cvt<<<dim3(VD / 32, CC / 32), dim3(32, 8), 0, stream>>>(Wv, WcatT + (size_t)1536 * CC, CC, VD);
  k_transpose_cvt<<<dim3(VD / 32, CC / 32), dim3(32, 8), 0, stream>>>(Wg, WcatT + (size_t)3072 * CC, CC, VD);
  k_transpose_cvt<<<dim3(CC / 32, VD / 32), dim3(32, 8), 0, stream>>>(Wo, WoT, VD, CC);

  // fused projection GEMM: [2048,2048] x [4608,2048]^T -> [2048,4608]
  k_gemm_bt<<<dim3(NCAT / 128, M / 128), 256, 0, stream>>>(hbf, WcatT, fpre, M, NCAT, CC);

  // beta / g
  k_ab<<<M, 64, 0, stream>>>(hidden, Wa, Wb, A_log, dt_bias, gdec, beta);

  // conv + silu (+norm for q,k)
  k_conv_silu<<<dim3(M, HH), 128, 0, stream>>>(fpre, NCAT, 0, qconv, qn, KD, 1);
  k_conv_silu<<<dim3(M, HH), 128, 0, stream>>>(fpre, NCAT, 768, kconv, kn, KD, 1);
  k_conv_silu<<<dim3(M, HH), 256, 0, stream>>>(fpre, NCAT, 1536, vconv, vn, VD, 0);

  // sequential scan
  k_scan<<<BB * HH, 256, 0, stream>>>(qn, kn, vn, beta, gdec, attn);

  // gated RMSNorm -> bf16
  k_gatenorm<<<dim3(M, HH), 256, 0, stream>>>(attn, fpre, onorm, ovd);

  // output projection: [2048,1536] x [2048,1536]^T -> [2048,2048]
  k_gemm_bt<<<dim3(CC / 128, M / 128), 256, 0, stream>>>(ovd, WoT, out, M, CC, VD);
}

// Round 2
// 901.317 us; speedup vs baseline: 2.9464x; 2.9464x over previous
//
#include <hip/hip_runtime.h>
#include <hip/hip_bf16.h>
#include <math.h>

typedef __bf16 bf16_t;
typedef __attribute__((ext_vector_type(8))) __bf16 bf16x8;
typedef __attribute__((ext_vector_type(4))) float f32x4;

#define GAS __attribute__((address_space(1)))
#define LAS __attribute__((address_space(3)))

#define BB 2
#define TT 1024
#define CC 2048
#define HH 6
#define KK 128
#define VV 256
#define KD 768
#define VD 1536
#define NQKV 3072
#define NCAT 4608
#define NC 16     // chunks per sequence
#define CL 64     // chunk length

__device__ __forceinline__ void gload_lds16(const void* g, void* l) {
  __builtin_amdgcn_global_load_lds((const GAS void*)g, (LAS void*)l, 16, 0, 0);
}

// ---------- f32 -> bf16 convert ----------
__global__ void k_cvt_bf16(const float* __restrict__ in, bf16_t* __restrict__ out, int n) {
  int i = (blockIdx.x * blockDim.x + threadIdx.x) * 4;
  if (i + 3 < n) {
    float4 v = *(const float4*)(in + i);
    out[i + 0] = (bf16_t)v.x;
    out[i + 1] = (bf16_t)v.y;
    out[i + 2] = (bf16_t)v.z;
    out[i + 3] = (bf16_t)v.w;
  }
}

// ---------- transpose [Kd,Nd] f32 -> [Nd,Kd] bf16 ----------
__global__ void k_transpose_cvt(const float* __restrict__ in, bf16_t* __restrict__ out,
                                int Kd, int Nd) {
  __shared__ float t[32][33];
  int n0 = blockIdx.x * 32, k0 = blockIdx.y * 32;
  int tx = threadIdx.x, ty = threadIdx.y;
#pragma unroll
  for (int i = 0; i < 32; i += 8)
    t[ty + i][tx] = in[(size_t)(k0 + ty + i) * Nd + n0 + tx];
  __syncthreads();
#pragma unroll
  for (int i = 0; i < 32; i += 8)
    out[(size_t)(n0 + ty + i) * Kd + k0 + tx] = (bf16_t)t[tx][ty + i];
}

// ---------- bf16 MFMA GEMM: C[M,N] = A[M,K] * B^T (B is [N,K]) ----------
__global__ __launch_bounds__(256, 2)
void k_gemm_bt(const bf16_t* __restrict__ A, const bf16_t* __restrict__ B,
               float* __restrict__ C, int M, int N, int K) {
  __shared__ __align__(16) bf16_t As[128 * 32];
  __shared__ __align__(16) bf16_t Bs[128 * 32];
  int tid = threadIdx.x;
  int wave = tid >> 6, lane = tid & 63;
  int wm = wave >> 1, wn = wave & 1;
  int by = blockIdx.y, bx = blockIdx.x;
  const bf16_t* Abase = A + (size_t)by * 128 * K;
  const bf16_t* Bbase = B + (size_t)bx * 128 * K;
  int kc = tid & 3;

  f32x4 acc[4][4];
#pragma unroll
  for (int i = 0; i < 4; ++i)
#pragma unroll
    for (int j = 0; j < 4; ++j) acc[i][j] = (f32x4){0.f, 0.f, 0.f, 0.f};

  for (int k0 = 0; k0 < K; k0 += 32) {
#pragma unroll
    for (int r = 0; r < 2; ++r) {
      int rowe = r * 64 + (tid >> 2);
      const bf16_t* ga = Abase + (size_t)rowe * K + k0 + kc * 8;
      const bf16_t* gb = Bbase + (size_t)rowe * K + k0 + kc * 8;
      gload_lds16(ga, As + (size_t)(r * 256 + wave * 64) * 8);
      gload_lds16(gb, Bs + (size_t)(r * 256 + wave * 64) * 8);
    }
    __syncthreads();
    int kg = lane >> 4, lr = lane & 15;
    bf16x8 af[4], bfv[4];
#pragma unroll
    for (int i = 0; i < 4; ++i) {
      af[i]  = *(const bf16x8*)(As + ((wm * 64 + i * 16 + lr) * 32 + kg * 8));
      bfv[i] = *(const bf16x8*)(Bs + ((wn * 64 + i * 16 + lr) * 32 + kg * 8));
    }
#pragma unroll
    for (int i = 0; i < 4; ++i)
#pragma unroll
      for (int j = 0; j < 4; ++j)
        acc[i][j] = __builtin_amdgcn_mfma_f32_16x16x32_bf16(af[i], bfv[j], acc[i][j], 0, 0, 0);
    __syncthreads();
  }

#pragma unroll
  for (int i = 0; i < 4; ++i) {
    int r0 = by * 128 + wm * 64 + i * 16 + ((lane >> 4) << 2);
#pragma unroll
    for (int j = 0; j < 4; ++j) {
      int c = bx * 128 + wn * 64 + j * 16 + (lane & 15);
      float* Cp = C + (size_t)r0 * N + c;
#pragma unroll
      for (int q = 0; q < 4; ++q) Cp[(size_t)q * N] = acc[i][j][q];
    }
  }
}

// ---------- beta / g ----------
__global__ __launch_bounds__(64)
void k_ab(const float* __restrict__ hidden, const float* __restrict__ Wa,
          const float* __restrict__ Wb, const float* __restrict__ A_log,
          const float* __restrict__ dt_bias, float* __restrict__ g_out,
          float* __restrict__ beta_out) {
  int row = blockIdx.x;
  int lane = threadIdx.x;
  float accA[6] = {0, 0, 0, 0, 0, 0};
  float accB[6] = {0, 0, 0, 0, 0, 0};
  const float* h = hidden + (size_t)row * CC;
  for (int c = lane; c < CC; c += 64) {
    float x = h[c];
    const float* wa = Wa + c * 6;
    const float* wb = Wb + c * 6;
#pragma unroll
    for (int j = 0; j < 6; ++j) {
      accA[j] += x * wa[j];
      accB[j] += x * wb[j];
    }
  }
#pragma unroll
  for (int j = 0; j < 6; ++j) {
    for (int off = 32; off; off >>= 1) {
      accA[j] += __shfl_down(accA[j], off);
      accB[j] += __shfl_down(accB[j], off);
    }
  }
  if (lane == 0) {
#pragma unroll
    for (int j = 0; j < 6; ++j) {
      float a = accA[j] + dt_bias[j];
      float sp = (a > 20.f) ? a : log1pf(expf(a));
      g_out[(size_t)row * 6 + j] = -expf(A_log[j]) * sp;
      beta_out[(size_t)row * 6 + j] = 1.f / (1.f + expf(-accB[j]));
    }
  }
}

// ---------- depthwise causal conv(4) + SiLU (+ optional L2 norm) ----------
__global__ void k_conv_silu(const float* __restrict__ pre, int ldpre, int col0,
                            const float* __restrict__ w, float* __restrict__ out,
                            int ld_out, int do_norm) {
  int row = blockIdx.x;     // b*T + t
  int t = row & (TT - 1);
  int h = blockIdx.y;
  int kk = threadIdx.x;
  int perH = blockDim.x;
  int ch = h * perH + kk;
  const float* wp = w + ch * 4;
  float y = 0.f;
#pragma unroll
  for (int i = 0; i < 4; ++i) {
    int tt = t - 3 + i;
    if (tt >= 0) y += wp[i] * pre[(size_t)(row - 3 + i) * ldpre + col0 + ch];
  }
  float s = y / (1.f + expf(-y));
  if (do_norm) {
    float ss = s * s;
#pragma unroll
    for (int off = 32; off; off >>= 1) ss += __shfl_down(ss, off);
    __shared__ float red[2];
    if ((threadIdx.x & 63) == 0) red[threadIdx.x >> 6] = ss;
    __syncthreads();
    float nrm = sqrtf(red[0] + red[1]);
    s = s / (nrm + 1e-6f);
  }
  out[(size_t)row * ld_out + ch] = s;
}

// ============ chunked gated delta rule ============
// Pass 1: per chunk, solve (I+M) D = diag(beta)[V | diag(e^b) K].
// Dv written in-place over vn; W -> Wbuf; cumsum(g) -> bcum.
__global__ __launch_bounds__(384, 1)
void k_chunk1(const float* __restrict__ kn, float* dv,
              const float* __restrict__ gdec, const float* __restrict__ beta,
              float* __restrict__ Wbuf, float* __restrict__ bcum) {
  __shared__ __align__(16) float Ms[64 * 64];
  __shared__ __align__(16) float dl[64 * 384];   // first 32KB doubles as ks
  __shared__ float bc[64], bet[64], gs[64];
  float* ks = dl;

  int tid = threadIdx.x;
  int bh = blockIdx.y, c = blockIdx.x;
  int b = bh / HH, h = bh % HH;
  int r0 = b * TT + c * CL;

  if (tid < 64) {
    gs[tid] = gdec[(size_t)(r0 + tid) * HH + h];
    bet[tid] = beta[(size_t)(r0 + tid) * HH + h];
  }
  __syncthreads();
  // inclusive scan of g over wave 0
  if (tid < 64) {
    float val = gs[tid];
#pragma unroll
    for (int off = 1; off < 64; off <<= 1) {
      float o = __shfl_up(val, off, 64);
      if (tid >= off) val += o;
    }
    bc[tid] = val;
    bcum[(size_t)(bh * NC + c) * CL + tid] = val;
  }
  // load k chunk into ks
  for (int idx = tid; idx < CL * KK; idx += 384) {
    int t = idx >> 7, kk = idx & 127;
    ks[idx] = kn[(size_t)(r0 + t) * KD + h * KK + kk];
  }
  __syncthreads();

  // M[t][s] = beta_t * e^{b_t-b_s} * (k_t . k_s), s<t
  for (int p = tid; p < 64 * 64; p += 384) {
    int t = p >> 6, s = p & 63;
    if (s < t) {
      const f32x4* a = (const f32x4*)&ks[t * 128];
      const f32x4* bb = (const f32x4*)&ks[s * 128];
      float acc = 0.f;
#pragma unroll
      for (int i = 0; i < 32; ++i) {
        f32x4 x = a[i], y = bb[i];
        acc += x[0] * y[0] + x[1] * y[1] + x[2] * y[2] + x[3] * y[3];
      }
      Ms[p] = bet[t] * __expf(bc[t] - bc[s]) * acc;
    }
  }
  __syncthreads();

  // fill RHS (overwrites ks region; k-part re-read from global)
  int col = tid;  // 0..383
  for (int t = 0; t < CL; ++t) {
    float r;
    if (col < 256)
      r = bet[t] * dv[(size_t)(r0 + t) * VD + h * VV + col];
    else
      r = bet[t] * __expf(bc[t]) * kn[(size_t)(r0 + t) * KD + h * KK + (col - 256)];
    dl[t * 384 + col] = r;
  }
  __syncthreads();

  // forward substitution (per-column independent; no barriers needed)
  for (int t = 1; t < CL; ++t) {
    const float* Mrow = &Ms[t * 64];
    float acc = 0.f;
    for (int s = 0; s < t; ++s) acc += Mrow[s] * dl[s * 384 + col];
    dl[t * 384 + col] -= acc;
  }

  // write out
  for (int t = 0; t < CL; ++t) {
    float d = dl[t * 384 + col];
    if (col < 256)
      dv[(size_t)(r0 + t) * VD + h * VV + col] = d;
    else
      Wbuf[((size_t)(bh * NC + c) * CL + t) * KK + (col - 256)] = d;
  }
}

// Pass 2: sequential state propagation S <- e^{bL} S + Khat^T (Dv - W S).
// Stores the chunk-START state for every chunk. grid (8 vtiles, 12 bh).
__global__ __launch_bounds__(256, 1)
void k_chunk2(const float* __restrict__ kn, const float* __restrict__ dv,
              const float* __restrict__ Wbuf, const float* __restrict__ bcum,
              float* __restrict__ states) {
  __shared__ __align__(16) float Sl[128 * 32];
  __shared__ __align__(16) float Zl[64 * 32];
  __shared__ __align__(16) float khat[64 * 128];
  __shared__ __align__(16) float Wl[64 * 128];
  __shared__ float scl[64];

  int tid = threadIdx.x;
  int vt = blockIdx.x, bh = blockIdx.y;
  int b = bh / HH, h = bh % HH;
  int j = tid & 31;

  for (int idx = tid; idx < 128 * 32; idx += 256) Sl[idx] = 0.f;

  for (int c = 0; c < NC; ++c) {
    int r0 = b * TT + c * CL;
    __syncthreads();
    // store chunk-start state
    for (int idx = tid; idx < 128 * 32; idx += 256) {
      int k = idx >> 5, jj = idx & 31;
      states[((size_t)(bh * NC + c) * KK + k) * VV + vt * 32 + jj] = Sl[idx];
    }
    if (tid < 64) scl[tid] = bcum[(size_t)(bh * NC + c) * CL + tid];
    __syncthreads();
    float bL = scl[63];
    for (int idx = tid; idx < CL * KK; idx += 256) {
      int t = idx >> 7, kk = idx & 127;
      Wl[idx] = Wbuf[((size_t)(bh * NC + c) * CL + t) * KK + kk];
      khat[idx] = __expf(bL - scl[t]) * kn[(size_t)(r0 + t) * KD + h * KK + kk];
    }
    __syncthreads();

    // Z = Dv - W*S  (64 x 32)
    {
      int ig = tid >> 5;  // 0..7, rows i = ig + 8p
      float dvv[8], yacc[8];
#pragma unroll
      for (int p = 0; p < 8; ++p) {
        int i = ig + 8 * p;
        dvv[p] = dv[(size_t)(r0 + i) * VD + h * VV + vt * 32 + j];
        yacc[p] = 0.f;
      }
      for (int k = 0; k < 128; ++k) {
        float sv = Sl[k * 32 + j];
#pragma unroll
        for (int p = 0; p < 8; ++p) yacc[p] += Wl[(ig + 8 * p) * 128 + k] * sv;
      }
#pragma unroll
      for (int p = 0; p < 8; ++p) Zl[(ig + 8 * p) * 32 + j] = dvv[p] - yacc[p];
    }
    __syncthreads();

    // S <- e^{bL} S + khat^T Z   (128 x 32)
    {
      int kg = tid >> 5;  // 0..7, rows k = kg + 8p (16 of them)
      float ebL = __expf(bL);
      float sacc[16];
#pragma unroll
      for (int p = 0; p < 16; ++p) sacc[p] = ebL * Sl[(kg + 8 * p) * 32 + j];
      for (int i = 0; i < 64; ++i) {
        float zv = Zl[i * 32 + j];
#pragma unroll
        for (int p = 0; p < 16; ++p) sacc[p] += khat[i * 128 + kg + 8 * p] * zv;
      }
#pragma unroll
      for (int p = 0; p < 16; ++p) Sl[(kg + 8 * p) * 32 + j] = sacc[p];
    }
  }
}

// Pass 3: outputs o = e^{b_t} q^T S0 + sum_{s<=t} P[t,s] (Dv - W S0)_s
__global__ __launch_bounds__(384, 1)
void k_chunk3(const float* __restrict__ qn, const float* __restrict__ kn,
              const float* __restrict__ dv, const float* __restrict__ Wbuf,
              const float* __restrict__ bcum, const float* __restrict__ states,
              float* __restrict__ attn) {
  __shared__ __align__(16) float qs[64 * 128];
  __shared__ __align__(16) float Pl[64 * 64];
  __shared__ __align__(16) float us[128 * 64];  // ks, then St tiles
  __shared__ __align__(16) float Wl[64 * 128];
  __shared__ __align__(16) float Zl[64 * 64];
  __shared__ float bcs[64];

  int tid = threadIdx.x;
  int bh = blockIdx.y, c = blockIdx.x;
  int b = bh / HH, h = bh % HH;
  int r0 = b * TT + c * CL;

  if (tid < 64) bcs[tid] = bcum[(size_t)(bh * NC + c) * CL + tid];
  for (int idx = tid; idx < CL * KK; idx += 384) {
    int t = idx >> 7, kk = idx & 127;
    qs[idx] = qn[(size_t)(r0 + t) * KD + h * KK + kk];
    us[idx] = kn[(size_t)(r0 + t) * KD + h * KK + kk];
    Wl[idx] = Wbuf[((size_t)(bh * NC + c) * CL + t) * KK + kk];
  }
  __syncthreads();

  // P[t][s] = (q_t . k_s) e^{b_t - b_s},  s <= t
  for (int p = tid; p < 64 * 64; p += 384) {
    int t = p >> 6, s = p & 63;
    float val = 0.f;
    if (s <= t) {
      const f32x4* a = (const f32x4*)&qs[t * 128];
      const f32x4* bb = (const f32x4*)&us[s * 128];
      float acc = 0.f;
#pragma unroll
      for (int i = 0; i < 32; ++i) {
        f32x4 x = a[i], y = bb[i];
        acc += x[0] * y[0] + x[1] * y[1] + x[2] * y[2] + x[3] * y[3];
      }
      val = acc * __expf(bcs[t] - bcs[s]);
    }
    Pl[p] = val;
  }
  __syncthreads();

  int j = tid & 63, g = tid >> 6;  // g in 0..5; rows t = g + 6p
  for (int jt = 0; jt < 4; ++jt) {
    // load state tile [128][64]
    for (int idx = tid; idx < 128 * 64; idx += 384) {
      int k = idx >> 6, jj = idx & 63;
      us[idx] = states[((size_t)(bh * NC + c) * KK + k) * VV + jt * 64 + jj];
    }
    __syncthreads();

    // Z[s][j] = Dv[s][j] - sum_k W[s][k] St[k][j]
    {
      float zacc[11];
#pragma unroll
      for (int p = 0; p < 11; ++p) {
        int s = g + 6 * p;
        zacc[p] = (s < 64) ? dv[(size_t)(r0 + s) * VD + h * VV + jt * 64 + j] : 0.f;
      }
      for (int k = 0; k < 128; ++k) {
        float uv = us[k * 64 + j];
#pragma unroll
        for (int p = 0; p < 11; ++p) {
          int s = g + 6 * p;
          if (s < 64) zacc[p] -= Wl[s * 128 + k] * uv;
        }
      }
#pragma unroll
      for (int p = 0; p < 11; ++p) {
        int s = g + 6 * p;
        if (s < 64) Zl[s * 64 + j] = zacc[p];
      }
    }
    __syncthreads();

    // o[t][j] = sum_{s<=t} P[t][s] Z[s][j] + e^{b_t} sum_k q[t][k] St[k][j]
    {
      float oacc[11], qacc[11];
#pragma unroll
      for (int p = 0; p < 11; ++p) { oacc[p] = 0.f; qacc[p] = 0.f; }
      for (int s = 0; s < 64; ++s) {
        float zv = Zl[s * 64 + j];
#pragma unroll
        for (int p = 0; p < 11; ++p) {
          int t = g + 6 * p;
          if (t < 64 && s <= t) oacc[p] += Pl[t * 64 + s] * zv;
        }
      }
      for (int k = 0; k < 128; ++k) {
        float uv = us[k * 64 + j];
#pragma unroll
        for (int p = 0; p < 11; ++p) {
          int t = g + 6 * p;
          if (t < 64) qacc[p] += qs[t * 128 + k] * uv;
        }
      }
#pragma unroll
      for (int p = 0; p < 11; ++p) {
        int t = g + 6 * p;
        if (t < 64)
          attn[(size_t)(r0 + t) * VD + h * VV + jt * 64 + j] =
              oacc[p] + __expf(bcs[t]) * qacc[p];
      }
    }
    __syncthreads();
  }
}

// ---------- gated RMSNorm + cast to bf16 ----------
__global__ __launch_bounds__(256)
void k_gatenorm(const float* __restrict__ attn, const float* __restrict__ fgate,
                const float* __restrict__ onorm_w, bf16_t* __restrict__ out) {
  int row = blockIdx.x;
  int h = blockIdx.y;
  int vi = threadIdx.x;
  float x = attn[(size_t)row * VD + h * VV + vi];
  float ss = x * x;
#pragma unroll
  for (int off = 32; off; off >>= 1) ss += __shfl_down(ss, off);
  __shared__ float red[4];
  if ((threadIdx.x & 63) == 0) red[threadIdx.x >> 6] = ss;
  __syncthreads();
  float tot = red[0] + red[1] + red[2] + red[3];
  float r = rsqrtf(tot / (float)VV + 1e-5f);
  float gate = fgate[(size_t)row * VD + h * VV + vi];
  float y = x * r * onorm_w[vi] * (gate / (1.f + expf(-gate)));
  out[(size_t)row * VD + h * VV + vi] = (bf16_t)y;
}

extern "C" void kernel_launch(void* const* d_in, const int* in_sizes, int n_in,
                              void* d_out, int out_size, void* d_ws, size_t ws_size,
                              hipStream_t stream) {
  const float* hidden = (const float*)d_in[0];
  const float* Wq = (const float*)d_in[1];
  const float* Wk = (const float*)d_in[2];
  const float* Wv = (const float*)d_in[3];
  const float* Wa = (const float*)d_in[4];
  const float* Wb = (const float*)d_in[5];
  const float* A_log = (const float*)d_in[6];
  const float* dt_bias = (const float*)d_in[7];
  const float* qconv = (const float*)d_in[8];
  const float* kconv = (const float*)d_in[9];
  const float* vconv = (const float*)d_in[10];
  const float* Wg = (const float*)d_in[11];
  const float* onorm = (const float*)d_in[12];
  const float* Wo = (const float*)d_in[13];
  float* out = (float*)d_out;

  char* ws = (char*)d_ws;
  size_t off = 0;
  auto alloc = [&](size_t bytes) {
    void* p = ws + off;
    off += (bytes + 255) & ~(size_t)255;
    return p;
  };
  const int M = BB * TT;  // 2048
  bf16_t* hbf   = (bf16_t*)alloc((size_t)M * CC * 2);
  bf16_t* WcatT = (bf16_t*)alloc((size_t)NCAT * CC * 2);
  bf16_t* WoT   = (bf16_t*)alloc((size_t)CC * VD * 2);
  float*  fqkv  = (float*) alloc((size_t)M * NQKV * 4);   // reused as states
  float*  fgate = (float*) alloc((size_t)M * VD * 4);
  float*  qn    = (float*) alloc((size_t)M * KD * 4);
  float*  kn    = (float*) alloc((size_t)M * KD * 4);
  float*  vn    = (float*) alloc((size_t)M * VD * 4);     // becomes Dv in pass 1
  float*  gdec  = (float*) alloc((size_t)M * HH * 4);
  float*  beta  = (float*) alloc((size_t)M * HH * 4);
  float*  attn  = (float*) alloc((size_t)M * VD * 4);
  bf16_t* ovd   = (bf16_t*)alloc((size_t)M * VD * 2);
  float*  Wbuf  = (float*) alloc((size_t)12 * NC * CL * KK * 4);
  float*  bcum  = (float*) alloc((size_t)12 * NC * CL * 4);
  float*  states = fqkv;  // 2048*3072 == 12*16*128*256 floats exactly

  // pre-pass: convert hidden, transpose+convert weights
  k_cvt_bf16<<<(M * CC / 4 + 255) / 256, 256, 0, stream>>>(hidden, hbf, M * CC);
  k_transpose_cvt<<<dim3(KD / 32, CC / 32), dim3(32, 8), 0, stream>>>(Wq, WcatT, CC, KD);
  k_transpose_cvt<<<dim3(KD / 32, CC / 32), dim3(32, 8), 0, stream>>>(Wk, WcatT + (size_t)768 * CC, CC, KD);
  k_transpose_cvt<<<dim3(VD / 32, CC / 32), dim3(32, 8), 0, stream>>>(Wv, WcatT + (size_t)1536 * CC, CC, VD);
  k_transpose_cvt<<<dim3(VD / 32, CC / 32), dim3(32, 8), 0, stream>>>(Wg, WcatT + (size_t)3072 * CC, CC, VD);
  k_transpose_cvt<<<dim3(CC / 32, VD / 32), dim3(32, 8), 0, stream>>>(Wo, WoT, VD, CC);

  // projections
  k_gemm_bt<<<dim3(NQKV / 128, M / 128), 256, 0, stream>>>(hbf, WcatT, fqkv, M, NQKV, CC);
  k_gemm_bt<<<dim3(VD / 128, M / 128), 256, 0, stream>>>(hbf, WcatT + (size_t)3072 * CC, fgate, M, VD, CC);

  // beta / g
  k_ab<<<M, 64, 0, stream>>>(hidden, Wa, Wb, A_log, dt_bias, gdec, beta);

  // conv + silu (+norm for q,k)
  k_conv_silu<<<dim3(M, HH), 128, 0, stream>>>(fqkv, NQKV, 0, qconv, qn, KD, 1);
  k_conv_silu<<<dim3(M, HH), 128, 0, stream>>>(fqkv, NQKV, 768, kconv, kn, KD, 1);
  k_conv_silu<<<dim3(M, HH), 256, 0, stream>>>(fqkv, NQKV, 1536, vconv, vn, VD, 0);

  // chunked gated delta rule (fqkv now dead -> states aliases it)
  k_chunk1<<<dim3(NC, 12), 384, 0, stream>>>(kn, vn, gdec, beta, Wbuf, bcum);
  k_chunk2<<<dim3(8, 12), 256, 0, stream>>>(kn, vn, Wbuf, bcum, states);
  k_chunk3<<<dim3(NC, 12), 384, 0, stream>>>(qn, kn, vn, Wbuf, bcum, states, attn);

  // gated RMSNorm -> bf16
  k_gatenorm<<<dim3(M, HH), 256, 0, stream>>>(attn, fgate, onorm, ovd);

  // output projection
  k_gemm_bt<<<dim3(CC / 128, M / 128), 256, 0, stream>>>(ovd, WoT, out, M, CC, VD);
}

// Round 3
// 337.362 us; speedup vs baseline: 7.8717x; 2.6717x over previous
//
#include <hip/hip_runtime.h>
#include <hip/hip_bf16.h>
#include <math.h>

typedef __bf16 bf16_t;
typedef __attribute__((ext_vector_type(8))) __bf16 bf16x8;
typedef __attribute__((ext_vector_type(4))) float f32x4;

#define GAS __attribute__((address_space(1)))
#define LAS __attribute__((address_space(3)))

#define BB 2
#define TT 1024
#define CC 2048
#define HH 6
#define KK 128
#define VV 256
#define KD 768
#define VD 1536
#define NQKV 3072
#define NCAT 4608
#define NC 16     // chunks per sequence
#define CL 64     // chunk length

__device__ __forceinline__ void gload_lds16(const void* g, void* l) {
  __builtin_amdgcn_global_load_lds((const GAS void*)g, (LAS void*)l, 16, 0, 0);
}

// ---------- f32 -> bf16 convert ----------
__global__ void k_cvt_bf16(const float* __restrict__ in, bf16_t* __restrict__ out, int n) {
  int i = (blockIdx.x * blockDim.x + threadIdx.x) * 4;
  if (i + 3 < n) {
    float4 v = *(const float4*)(in + i);
    out[i + 0] = (bf16_t)v.x;
    out[i + 1] = (bf16_t)v.y;
    out[i + 2] = (bf16_t)v.z;
    out[i + 3] = (bf16_t)v.w;
  }
}

// ---------- transpose [Kd,Nd] f32 -> [Nd,Kd] bf16 ----------
__global__ void k_transpose_cvt(const float* __restrict__ in, bf16_t* __restrict__ out,
                                int Kd, int Nd) {
  __shared__ float t[32][33];
  int n0 = blockIdx.x * 32, k0 = blockIdx.y * 32;
  int tx = threadIdx.x, ty = threadIdx.y;
#pragma unroll
  for (int i = 0; i < 32; i += 8)
    t[ty + i][tx] = in[(size_t)(k0 + ty + i) * Nd + n0 + tx];
  __syncthreads();
#pragma unroll
  for (int i = 0; i < 32; i += 8)
    out[(size_t)(n0 + ty + i) * Kd + k0 + tx] = (bf16_t)t[tx][ty + i];
}

// ---------- bf16 MFMA GEMM: C[M,N] = A[M,K] * B^T (B is [N,K]) ----------
__global__ __launch_bounds__(256, 2)
void k_gemm_bt(const bf16_t* __restrict__ A, const bf16_t* __restrict__ B,
               float* __restrict__ C, int M, int N, int K) {
  __shared__ __align__(16) bf16_t As[128 * 32];
  __shared__ __align__(16) bf16_t Bs[128 * 32];
  int tid = threadIdx.x;
  int wave = tid >> 6, lane = tid & 63;
  int wm = wave >> 1, wn = wave & 1;
  int by = blockIdx.y, bx = blockIdx.x;
  const bf16_t* Abase = A + (size_t)by * 128 * K;
  const bf16_t* Bbase = B + (size_t)bx * 128 * K;
  int kc = tid & 3;

  f32x4 acc[4][4];
#pragma unroll
  for (int i = 0; i < 4; ++i)
#pragma unroll
    for (int j = 0; j < 4; ++j) acc[i][j] = (f32x4){0.f, 0.f, 0.f, 0.f};

  for (int k0 = 0; k0 < K; k0 += 32) {
#pragma unroll
    for (int r = 0; r < 2; ++r) {
      int rowe = r * 64 + (tid >> 2);
      const bf16_t* ga = Abase + (size_t)rowe * K + k0 + kc * 8;
      const bf16_t* gb = Bbase + (size_t)rowe * K + k0 + kc * 8;
      gload_lds16(ga, As + (size_t)(r * 256 + wave * 64) * 8);
      gload_lds16(gb, Bs + (size_t)(r * 256 + wave * 64) * 8);
    }
    __syncthreads();
    int kg = lane >> 4, lr = lane & 15;
    bf16x8 af[4], bfv[4];
#pragma unroll
    for (int i = 0; i < 4; ++i) {
      af[i]  = *(const bf16x8*)(As + ((wm * 64 + i * 16 + lr) * 32 + kg * 8));
      bfv[i] = *(const bf16x8*)(Bs + ((wn * 64 + i * 16 + lr) * 32 + kg * 8));
    }
#pragma unroll
    for (int i = 0; i < 4; ++i)
#pragma unroll
      for (int j = 0; j < 4; ++j)
        acc[i][j] = __builtin_amdgcn_mfma_f32_16x16x32_bf16(af[i], bfv[j], acc[i][j], 0, 0, 0);
    __syncthreads();
  }

#pragma unroll
  for (int i = 0; i < 4; ++i) {
    int r0 = by * 128 + wm * 64 + i * 16 + ((lane >> 4) << 2);
#pragma unroll
    for (int j = 0; j < 4; ++j) {
      int c = bx * 128 + wn * 64 + j * 16 + (lane & 15);
      float* Cp = C + (size_t)r0 * N + c;
#pragma unroll
      for (int q = 0; q < 4; ++q) Cp[(size_t)q * N] = acc[i][j][q];
    }
  }
}

// ---------- beta / g ----------
__global__ __launch_bounds__(64)
void k_ab(const float* __restrict__ hidden, const float* __restrict__ Wa,
          const float* __restrict__ Wb, const float* __restrict__ A_log,
          const float* __restrict__ dt_bias, float* __restrict__ g_out,
          float* __restrict__ beta_out) {
  int row = blockIdx.x;
  int lane = threadIdx.x;
  float accA[6] = {0, 0, 0, 0, 0, 0};
  float accB[6] = {0, 0, 0, 0, 0, 0};
  const float* h = hidden + (size_t)row * CC;
  for (int c = lane; c < CC; c += 64) {
    float x = h[c];
    const float* wa = Wa + c * 6;
    const float* wb = Wb + c * 6;
#pragma unroll
    for (int j = 0; j < 6; ++j) {
      accA[j] += x * wa[j];
      accB[j] += x * wb[j];
    }
  }
#pragma unroll
  for (int j = 0; j < 6; ++j) {
    for (int off = 32; off; off >>= 1) {
      accA[j] += __shfl_down(accA[j], off);
      accB[j] += __shfl_down(accB[j], off);
    }
  }
  if (lane == 0) {
#pragma unroll
    for (int j = 0; j < 6; ++j) {
      float a = accA[j] + dt_bias[j];
      float sp = (a > 20.f) ? a : log1pf(expf(a));
      g_out[(size_t)row * 6 + j] = -expf(A_log[j]) * sp;
      beta_out[(size_t)row * 6 + j] = 1.f / (1.f + expf(-accB[j]));
    }
  }
}

// ---------- depthwise causal conv(4) + SiLU (+ optional L2 norm); optional f32/bf16 outs ----------
__global__ void k_conv_silu(const float* __restrict__ pre, int ldpre, int col0,
                            const float* __restrict__ w, float* __restrict__ out,
                            bf16_t* __restrict__ out16, int ld_out, int do_norm) {
  int row = blockIdx.x;     // b*T + t
  int t = row & (TT - 1);
  int h = blockIdx.y;
  int kk = threadIdx.x;
  int perH = blockDim.x;
  int ch = h * perH + kk;
  const float* wp = w + ch * 4;
  float y = 0.f;
#pragma unroll
  for (int i = 0; i < 4; ++i) {
    int tt = t - 3 + i;
    if (tt >= 0) y += wp[i] * pre[(size_t)(row - 3 + i) * ldpre + col0 + ch];
  }
  float s = y / (1.f + expf(-y));
  if (do_norm) {
    float ss = s * s;
#pragma unroll
    for (int off = 32; off; off >>= 1) ss += __shfl_down(ss, off);
    __shared__ float red[2];
    if ((threadIdx.x & 63) == 0) red[threadIdx.x >> 6] = ss;
    __syncthreads();
    float nrm = sqrtf(red[0] + red[1]);
    s = s / (nrm + 1e-6f);
  }
  if (out) out[(size_t)row * ld_out + ch] = s;
  if (out16) out16[(size_t)row * ld_out + ch] = (bf16_t)s;
}

// ============ chunked gated delta rule ============
// Pass 1: per chunk, solve (I+M) D = diag(beta)[V | diag(e^b) K].
// Dv in-place over vn; -W -> Wn16 (bf16 [t][k]); khatT -> khatT16 (bf16 [k][t]); cumsum -> bcum.
__global__ __launch_bounds__(384, 1)
void k_chunk1(const float* __restrict__ kn, float* dv,
              const float* __restrict__ gdec, const float* __restrict__ beta,
              bf16_t* __restrict__ Wn16, bf16_t* __restrict__ khatT16,
              float* __restrict__ bcum) {
  __shared__ __align__(16) float Ms[64 * 64];
  __shared__ __align__(16) float dl[64 * 384];
  __shared__ __align__(16) float ksl[64 * 132];   // +4 pad: conflict-free dot reads
  __shared__ float bc[64], bet[64];

  int tid = threadIdx.x;
  int bh = blockIdx.y, c = blockIdx.x;
  int b = bh / HH, h = bh % HH;
  int r0 = b * TT + c * CL;
  size_t cb = (size_t)bh * NC + c;

  if (tid < 64) {
    float val = gdec[(size_t)(r0 + tid) * HH + h];
    bet[tid] = beta[(size_t)(r0 + tid) * HH + h];
#pragma unroll
    for (int off = 1; off < 64; off <<= 1) {
      float o = __shfl_up(val, off, 64);
      if (tid >= off) val += o;
    }
    bc[tid] = val;
    bcum[cb * CL + tid] = val;
  }
  for (int idx = tid; idx < CL * KK; idx += 384) {
    int t = idx >> 7, kk = idx & 127;
    ksl[t * 132 + kk] = kn[(size_t)(r0 + t) * KD + h * KK + kk];
  }
  __syncthreads();
  float bL = bc[63];

  // khatT16[k][t] = bf16(e^{bL-b_t} k[t][k])
  for (int idx = tid; idx < KK * CL; idx += 384) {
    int k = idx >> 6, t = idx & 63;
    khatT16[cb * (KK * CL) + idx] = (bf16_t)(__expf(bL - bc[t]) * ksl[t * 132 + k]);
  }

  // M[t][s] = beta_t e^{b_t-b_s} (k_t.k_s), s<t
  for (int p = tid; p < 64 * 64; p += 384) {
    int t = p >> 6, s = p & 63;
    if (s < t) {
      const f32x4* a = (const f32x4*)&ksl[t * 132];
      const f32x4* bb = (const f32x4*)&ksl[s * 132];
      float acc = 0.f;
#pragma unroll
      for (int i = 0; i < 32; ++i) {
        f32x4 x = a[i], y = bb[i];
        acc += x[0] * y[0] + x[1] * y[1] + x[2] * y[2] + x[3] * y[3];
      }
      Ms[p] = bet[t] * __expf(bc[t] - bc[s]) * acc;
    }
  }

  // RHS
  int col = tid;
  for (int t = 0; t < CL; ++t) {
    float r;
    if (col < 256)
      r = bet[t] * dv[(size_t)(r0 + t) * VD + h * VV + col];
    else
      r = bet[t] * __expf(bc[t]) * ksl[t * 132 + (col - 256)];
    dl[t * 384 + col] = r;
  }
  __syncthreads();

  // forward substitution (per-column independent)
  for (int t = 1; t < CL; ++t) {
    const float* Mrow = &Ms[t * 64];
    float acc = 0.f;
    for (int s = 0; s < t; ++s) acc += Mrow[s] * dl[s * 384 + col];
    dl[t * 384 + col] -= acc;
  }

  // write out
  for (int t = 0; t < CL; ++t) {
    float d = dl[t * 384 + col];
    if (col < 256)
      dv[(size_t)(r0 + t) * VD + h * VV + col] = d;
    else
      Wn16[(cb * CL + t) * KK + (col - 256)] = (bf16_t)(-d);
  }
}

// Pass 2: MFMA state propagation. Grid (8 vtiles of 32, 12 bh), 256 thr (4 waves).
// S (f32) lives in accumulators across all 16 chunks (k-split across waves).
// Emits chunk-start states S0^T (bf16 [v][k]) and Zt (bf16 [v][t]).
__global__ __launch_bounds__(256, 1)
void k_chunk2(const float* __restrict__ dv, const bf16_t* __restrict__ Wn16,
              const bf16_t* __restrict__ khatT16, const float* __restrict__ bcum,
              bf16_t* __restrict__ states, bf16_t* __restrict__ Zt) {
  __shared__ __align__(16) bf16_t St[32 * 128];   // [v][k], XOR-swizzled
  __shared__ __align__(16) bf16_t Zl[32 * 64];    // [v][t], XOR-swizzled
  int tid = threadIdx.x;
  int vt = blockIdx.x, bh = blockIdx.y;
  int b = bh / HH, h = bh % HH;
  int wq = tid >> 6, l = tid & 63;
  int lr = l & 15, lg = l >> 4;

  f32x4 acc[2][2];
#pragma unroll
  for (int kf = 0; kf < 2; ++kf)
#pragma unroll
    for (int vf = 0; vf < 2; ++vf) acc[kf][vf] = (f32x4){0.f, 0.f, 0.f, 0.f};

  for (int c = 0; c < NC; ++c) {
    size_t cb = (size_t)bh * NC + c;
    int r0 = b * TT + c * CL;
    float ebL = __expf(bcum[cb * CL + 63]);

    // A: S acc -> St bf16 (swizzled)
#pragma unroll
    for (int kf = 0; kf < 2; ++kf)
#pragma unroll
      for (int vf = 0; vf < 2; ++vf)
#pragma unroll
        for (int q = 0; q < 4; ++q) {
          int k = wq * 32 + kf * 16 + lg * 4 + q;
          int v = vf * 16 + lr;
          *(bf16_t*)((char*)St + v * 256 + ((k * 2) ^ ((v & 7) << 4))) = (bf16_t)acc[kf][vf][q];
        }
    __syncthreads();

    // B: states copy (S0^T for pass 3)
#pragma unroll
    for (int it = 0; it < 2; ++it) {
      int idx = tid + it * 256;
      int v = idx >> 4, slot = idx & 15;
      bf16x8 val = *(const bf16x8*)((const char*)St + v * 256 + ((slot * 16) ^ ((v & 7) << 4)));
      *(bf16x8*)(states + ((size_t)cb * 256 + vt * 32 + v) * 128 + slot * 8) = val;
    }

    // Z = Dv + (-W) * S  : per wave 16t x 32v
    f32x4 zacc[2];
#pragma unroll
    for (int vf = 0; vf < 2; ++vf)
#pragma unroll
      for (int q = 0; q < 4; ++q) {
        int t = wq * 16 + lg * 4 + q;
        zacc[vf][q] = dv[(size_t)(r0 + t) * VD + h * VV + vt * 32 + vf * 16 + lr];
      }
#pragma unroll
    for (int ks_ = 0; ks_ < 4; ++ks_) {
      bf16x8 aW = *(const bf16x8*)(Wn16 + (cb * CL + wq * 16 + lr) * KK + ks_ * 32 + lg * 8);
#pragma unroll
      for (int vf = 0; vf < 2; ++vf) {
        int v = vf * 16 + lr;
        bf16x8 bS = *(const bf16x8*)((const char*)St + v * 256 + (((ks_ * 32 + lg * 8) * 2) ^ ((v & 7) << 4)));
        zacc[vf] = __builtin_amdgcn_mfma_f32_16x16x32_bf16(aW, bS, zacc[vf], 0, 0, 0);
      }
    }
    // Zl write (bf16 [v][t] swizzled)
#pragma unroll
    for (int vf = 0; vf < 2; ++vf)
#pragma unroll
      for (int q = 0; q < 4; ++q) {
        int t = wq * 16 + lg * 4 + q;
        int v = vf * 16 + lr;
        *(bf16_t*)((char*)Zl + v * 128 + ((t * 2) ^ ((v & 7) << 4))) = (bf16_t)zacc[vf][q];
      }
    __syncthreads();

    // D: Zt copy to global
    {
      int v = tid >> 3, slot = tid & 7;
      bf16x8 val = *(const bf16x8*)((const char*)Zl + v * 128 + ((slot * 16) ^ ((v & 7) << 4)));
      *(bf16x8*)(Zt + ((size_t)cb * 256 + vt * 32 + v) * 64 + slot * 8) = val;
    }
    // S decay + S += khatT * Z
#pragma unroll
    for (int kf = 0; kf < 2; ++kf)
#pragma unroll
      for (int vf = 0; vf < 2; ++vf)
#pragma unroll
        for (int q = 0; q < 4; ++q) acc[kf][vf][q] *= ebL;
#pragma unroll
    for (int ts = 0; ts < 2; ++ts) {
      bf16x8 aK[2], bZ[2];
#pragma unroll
      for (int kf = 0; kf < 2; ++kf)
        aK[kf] = *(const bf16x8*)(khatT16 + (cb * KK + wq * 32 + kf * 16 + lr) * CL + ts * 32 + lg * 8);
#pragma unroll
      for (int vf = 0; vf < 2; ++vf) {
        int v = vf * 16 + lr;
        bZ[vf] = *(const bf16x8*)((const char*)Zl + v * 128 + (((ts * 32 + lg * 8) * 2) ^ ((v & 7) << 4)));
      }
#pragma unroll
      for (int kf = 0; kf < 2; ++kf)
#pragma unroll
        for (int vf = 0; vf < 2; ++vf)
          acc[kf][vf] = __builtin_amdgcn_mfma_f32_16x16x32_bf16(aK[kf], bZ[vf], acc[kf][vf], 0, 0, 0);
    }
  }
}

// Pass 3: o = e^{b_t} q^T S0 + P Z, all MFMA. Grid (NC, 12), 256 thr.
__global__ __launch_bounds__(256, 1)
void k_chunk3(const bf16_t* __restrict__ qb16, const bf16_t* __restrict__ kb16,
              const bf16_t* __restrict__ Zt, const bf16_t* __restrict__ states,
              const float* __restrict__ bcum, float* __restrict__ attn) {
  __shared__ __align__(16) bf16_t qs[64 * 128];   // [t][k] swizzled via pre-XOR source
  __shared__ __align__(16) bf16_t ksh[64 * 128];
  __shared__ __align__(16) bf16_t Pl[64 * 64];    // [t][s] swizzled
  __shared__ float bcs[64];

  int tid = threadIdx.x;
  int c = blockIdx.x, bh = blockIdx.y;
  int b = bh / HH, h = bh % HH;
  int r0 = b * TT + c * CL;
  size_t cb = (size_t)bh * NC + c;
  int wq = tid >> 6, l = tid & 63;
  int lr = l & 15, lg = l >> 4;

  if (tid < 64) bcs[tid] = bcum[cb * CL + tid];
#pragma unroll
  for (int it = 0; it < 4; ++it) {
    int idx = it * 256 + tid;
    int t = idx >> 4, p = idx & 15;
    int kslot = p ^ (t & 7);
    gload_lds16(qb16 + (size_t)(r0 + t) * KD + h * KK + kslot * 8,
                qs + (size_t)(it * 256 + wq * 64) * 8);
    gload_lds16(kb16 + (size_t)(r0 + t) * KD + h * KK + kslot * 8,
                ksh + (size_t)(it * 256 + wq * 64) * 8);
  }
  __syncthreads();

  // P = mask(q k^T) * e^{b_t-b_s}; wave wq covers t rows wq*16..+15
  f32x4 pacc[4];
#pragma unroll
  for (int sf = 0; sf < 4; ++sf) pacc[sf] = (f32x4){0.f, 0.f, 0.f, 0.f};
#pragma unroll
  for (int ks_ = 0; ks_ < 4; ++ks_) {
    int trow = wq * 16 + lr;
    bf16x8 aQ = *(const bf16x8*)((const char*)qs + trow * 256 + (((ks_ * 4 + lg) * 16) ^ ((trow & 7) << 4)));
#pragma unroll
    for (int sf = 0; sf < 4; ++sf) {
      int srow = sf * 16 + lr;
      bf16x8 bK = *(const bf16x8*)((const char*)ksh + srow * 256 + (((ks_ * 4 + lg) * 16) ^ ((srow & 7) << 4)));
      pacc[sf] = __builtin_amdgcn_mfma_f32_16x16x32_bf16(aQ, bK, pacc[sf], 0, 0, 0);
    }
  }
#pragma unroll
  for (int sf = 0; sf < 4; ++sf)
#pragma unroll
    for (int q = 0; q < 4; ++q) {
      int t = wq * 16 + lg * 4 + q;
      int s = sf * 16 + lr;
      float val = (s <= t) ? pacc[sf][q] * __expf(bcs[t] - bcs[s]) : 0.f;
      *(bf16_t*)((char*)Pl + t * 128 + ((s * 2) ^ ((t & 7) << 4))) = (bf16_t)val;
    }
  __syncthreads();

  // O: wave wq covers v cols wq*64..+63; oacc = qhat*S0^T + P*Zt
  f32x4 oacc[4][4];
#pragma unroll
  for (int ti = 0; ti < 4; ++ti)
#pragma unroll
    for (int vj = 0; vj < 4; ++vj) oacc[ti][vj] = (f32x4){0.f, 0.f, 0.f, 0.f};

#pragma unroll
  for (int ks_ = 0; ks_ < 4; ++ks_) {
    bf16x8 aQ[4];
#pragma unroll
    for (int ti = 0; ti < 4; ++ti) {
      int t = ti * 16 + lr;
      union { bf16x8 v; bf16_t e[8]; } u;
      u.v = *(const bf16x8*)((const char*)qs + t * 256 + (((ks_ * 4 + lg) * 16) ^ ((t & 7) << 4)));
      float eb = __expf(bcs[t]);
#pragma unroll
      for (int e = 0; e < 8; ++e) u.e[e] = (bf16_t)((float)u.e[e] * eb);
      aQ[ti] = u.v;
    }
#pragma unroll
    for (int vj = 0; vj < 4; ++vj) {
      int vrow = wq * 64 + vj * 16 + lr;
      bf16x8 bS = *(const bf16x8*)(states + ((size_t)cb * 256 + vrow) * 128 + ks_ * 32 + lg * 8);
#pragma unroll
      for (int ti = 0; ti < 4; ++ti)
        oacc[ti][vj] = __builtin_amdgcn_mfma_f32_16x16x32_bf16(aQ[ti], bS, oacc[ti][vj], 0, 0, 0);
    }
  }
#pragma unroll
  for (int ts = 0; ts < 2; ++ts) {
    bf16x8 aP[4];
#pragma unroll
    for (int ti = 0; ti < 4; ++ti) {
      int t = ti * 16 + lr;
      aP[ti] = *(const bf16x8*)((const char*)Pl + t * 128 + (((ts * 4 + lg) * 16) ^ ((t & 7) << 4)));
    }
#pragma unroll
    for (int vj = 0; vj < 4; ++vj) {
      int vrow = wq * 64 + vj * 16 + lr;
      bf16x8 bZ = *(const bf16x8*)(Zt + ((size_t)cb * 256 + vrow) * 64 + ts * 32 + lg * 8);
#pragma unroll
      for (int ti = 0; ti < 4; ++ti)
        oacc[ti][vj] = __builtin_amdgcn_mfma_f32_16x16x32_bf16(aP[ti], bZ, oacc[ti][vj], 0, 0, 0);
    }
  }
#pragma unroll
  for (int ti = 0; ti < 4; ++ti)
#pragma unroll
    for (int vj = 0; vj < 4; ++vj)
#pragma unroll
      for (int q = 0; q < 4; ++q) {
        int t = ti * 16 + lg * 4 + q;
        int v = wq * 64 + vj * 16 + lr;
        attn[(size_t)(r0 + t) * VD + h * VV + v] = oacc[ti][vj][q];
      }
}

// ---------- gated RMSNorm + cast to bf16 ----------
__global__ __launch_bounds__(256)
void k_gatenorm(const float* __restrict__ attn, const float* __restrict__ fgate,
                const float* __restrict__ onorm_w, bf16_t* __restrict__ out) {
  int row = blockIdx.x;
  int h = blockIdx.y;
  int vi = threadIdx.x;
  float x = attn[(size_t)row * VD + h * VV + vi];
  float ss = x * x;
#pragma unroll
  for (int off = 32; off; off >>= 1) ss += __shfl_down(ss, off);
  __shared__ float red[4];
  if ((threadIdx.x & 63) == 0) red[threadIdx.x >> 6] = ss;
  __syncthreads();
  float tot = red[0] + red[1] + red[2] + red[3];
  float r = rsqrtf(tot / (float)VV + 1e-5f);
  float gate = fgate[(size_t)row * VD + h * VV + vi];
  float y = x * r * onorm_w[vi] * (gate / (1.f + expf(-gate)));
  out[(size_t)row * VD + h * VV + vi] = (bf16_t)y;
}

extern "C" void kernel_launch(void* const* d_in, const int* in_sizes, int n_in,
                              void* d_out, int out_size, void* d_ws, size_t ws_size,
                              hipStream_t stream) {
  const float* hidden = (const float*)d_in[0];
  const float* Wq = (const float*)d_in[1];
  const float* Wk = (const float*)d_in[2];
  const float* Wv = (const float*)d_in[3];
  const float* Wa = (const float*)d_in[4];
  const float* Wb = (const float*)d_in[5];
  const float* A_log = (const float*)d_in[6];
  const float* dt_bias = (const float*)d_in[7];
  const float* qconv = (const float*)d_in[8];
  const float* kconv = (const float*)d_in[9];
  const float* vconv = (const float*)d_in[10];
  const float* Wg = (const float*)d_in[11];
  const float* onorm = (const float*)d_in[12];
  const float* Wo = (const float*)d_in[13];
  float* out = (float*)d_out;

  char* ws = (char*)d_ws;
  size_t off = 0;
  auto alloc = [&](size_t bytes) {
    void* p = ws + off;
    off += (bytes + 255) & ~(size_t)255;
    return p;
  };
  const int M = BB * TT;  // 2048
  bf16_t* hbf   = (bf16_t*)alloc((size_t)M * CC * 2);       // aliased by Wn16/khatT16 later
  bf16_t* WcatT = (bf16_t*)alloc((size_t)NCAT * CC * 2);
  bf16_t* WoT   = (bf16_t*)alloc((size_t)CC * VD * 2);
  float*  fqkv  = (float*) alloc((size_t)M * NQKV * 4);     // aliased by states+attn later
  float*  fgate = (float*) alloc((size_t)M * VD * 4);
  float*  kn    = (float*) alloc((size_t)M * KD * 4);       // aliased by Zt later
  float*  vn    = (float*) alloc((size_t)M * VD * 4);       // becomes Dv in pass 1
  float*  gdec  = (float*) alloc((size_t)M * HH * 4);
  float*  beta  = (float*) alloc((size_t)M * HH * 4);
  bf16_t* ovd   = (bf16_t*)alloc((size_t)M * VD * 2);
  bf16_t* qb16  = (bf16_t*)alloc((size_t)M * KD * 2);
  bf16_t* kb16  = (bf16_t*)alloc((size_t)M * KD * 2);
  float*  bcum  = (float*) alloc((size_t)12 * NC * CL * 4);

  // aliases (stream-ordered lifetime separation):
  bf16_t* Wn16    = (bf16_t*)hbf;                    // 12*16*64*128 bf16 = 3.15MB
  bf16_t* khatT16 = Wn16 + (size_t)12 * NC * CL * KK; // +3.15MB (hbf is 8.4MB)
  bf16_t* states  = (bf16_t*)fqkv;                   // 12*16*256*128 bf16 = 12.6MB
  float*  attn    = (float*)((char*)fqkv + (size_t)12 * NC * VV * KK * 2);
  bf16_t* Zt      = (bf16_t*)kn;                     // 12*16*256*64 bf16 = 6.3MB

  // pre-pass
  k_cvt_bf16<<<(M * CC / 4 + 255) / 256, 256, 0, stream>>>(hidden, hbf, M * CC);
  k_transpose_cvt<<<dim3(KD / 32, CC / 32), dim3(32, 8), 0, stream>>>(Wq, WcatT, CC, KD);
  k_transpose_cvt<<<dim3(KD / 32, CC / 32), dim3(32, 8), 0, stream>>>(Wk, WcatT + (size_t)768 * CC, CC, KD);
  k_transpose_cvt<<<dim3(VD / 32, CC / 32), dim3(32, 8), 0, stream>>>(Wv, WcatT + (size_t)1536 * CC, CC, VD);
  k_transpose_cvt<<<dim3(VD / 32, CC / 32), dim3(32, 8), 0, stream>>>(Wg, WcatT + (size_t)3072 * CC, CC, VD);
  k_transpose_cvt<<<dim3(CC / 32, VD / 32), dim3(32, 8), 0, stream>>>(Wo, WoT, VD, CC);

  // projections
  k_gemm_bt<<<dim3(NQKV / 128, M / 128), 256, 0, stream>>>(hbf, WcatT, fqkv, M, NQKV, CC);
  k_gemm_bt<<<dim3(VD / 128, M / 128), 256, 0, stream>>>(hbf, WcatT + (size_t)3072 * CC, fgate, M, VD, CC);

  // beta / g
  k_ab<<<M, 64, 0, stream>>>(hidden, Wa, Wb, A_log, dt_bias, gdec, beta);

  // conv + silu (+norm for q,k)
  k_conv_silu<<<dim3(M, HH), 128, 0, stream>>>(fqkv, NQKV, 0, qconv, nullptr, qb16, KD, 1);
  k_conv_silu<<<dim3(M, HH), 128, 0, stream>>>(fqkv, NQKV, 768, kconv, kn, kb16, KD, 1);
  k_conv_silu<<<dim3(M, HH), 256, 0, stream>>>(fqkv, NQKV, 1536, vconv, vn, nullptr, VD, 0);

  // chunked gated delta rule (hbf dead -> Wn16/khatT16; fqkv dead -> states/attn; kn dead after c1 -> Zt)
  k_chunk1<<<dim3(NC, 12), 384, 0, stream>>>(kn, vn, gdec, beta, Wn16, khatT16, bcum);
  k_chunk2<<<dim3(8, 12), 256, 0, stream>>>(vn, Wn16, khatT16, bcum, states, Zt);
  k_chunk3<<<dim3(NC, 12), 256, 0, stream>>>(qb16, kb16, Zt, states, bcum, attn);

  // gated RMSNorm -> bf16
  k_gatenorm<<<dim3(M, HH), 256, 0, stream>>>(attn, fgate, onorm, ovd);

  // output projection
  k_gemm_bt<<<dim3(CC / 128, M / 128), 256, 0, stream>>>(ovd, WoT, out, M, CC, VD);
}

// Round 4
// 281.065 us; speedup vs baseline: 9.4484x; 1.2003x over previous
//
#include <hip/hip_runtime.h>
#include <hip/hip_bf16.h>
#include <math.h>

typedef __bf16 bf16_t;
typedef __attribute__((ext_vector_type(8))) __bf16 bf16x8;
typedef __attribute__((ext_vector_type(4))) float f32x4;

#define GAS __attribute__((address_space(1)))
#define LAS __attribute__((address_space(3)))

#define BB 2
#define TT 1024
#define CC 2048
#define HH 6
#define KK 128
#define VV 256
#define KD 768
#define VD 1536
#define NQKV 3072
#define NCAT 4608
#define NC 16     // chunks per sequence
#define CL 64     // chunk length

__device__ __forceinline__ void gload_lds16(const void* g, void* l) {
  __builtin_amdgcn_global_load_lds((const GAS void*)g, (LAS void*)l, 16, 0, 0);
}

// ---------- f32 -> bf16 convert ----------
__global__ void k_cvt_bf16(const float* __restrict__ in, bf16_t* __restrict__ out, int n) {
  int i = (blockIdx.x * blockDim.x + threadIdx.x) * 4;
  if (i + 3 < n) {
    float4 v = *(const float4*)(in + i);
    out[i + 0] = (bf16_t)v.x;
    out[i + 1] = (bf16_t)v.y;
    out[i + 2] = (bf16_t)v.z;
    out[i + 3] = (bf16_t)v.w;
  }
}

// ---------- transpose [Kd,Nd] f32 -> [Nd,Kd] bf16 ----------
__global__ void k_transpose_cvt(const float* __restrict__ in, bf16_t* __restrict__ out,
                                int Kd, int Nd) {
  __shared__ float t[32][33];
  int n0 = blockIdx.x * 32, k0 = blockIdx.y * 32;
  int tx = threadIdx.x, ty = threadIdx.y;
#pragma unroll
  for (int i = 0; i < 32; i += 8)
    t[ty + i][tx] = in[(size_t)(k0 + ty + i) * Nd + n0 + tx];
  __syncthreads();
#pragma unroll
  for (int i = 0; i < 32; i += 8)
    out[(size_t)(n0 + ty + i) * Kd + k0 + tx] = (bf16_t)t[tx][ty + i];
}

// ---------- bf16 MFMA GEMM: C[M,N] = A[M,K] * B^T (B is [N,K]) ----------
__global__ __launch_bounds__(256, 2)
void k_gemm_bt(const bf16_t* __restrict__ A, const bf16_t* __restrict__ B,
               float* __restrict__ C, int M, int N, int K) {
  __shared__ __align__(16) bf16_t As[128 * 32];
  __shared__ __align__(16) bf16_t Bs[128 * 32];
  int tid = threadIdx.x;
  int wave = tid >> 6, lane = tid & 63;
  int wm = wave >> 1, wn = wave & 1;
  int by = blockIdx.y, bx = blockIdx.x;
  const bf16_t* Abase = A + (size_t)by * 128 * K;
  const bf16_t* Bbase = B + (size_t)bx * 128 * K;
  int kc = tid & 3;

  f32x4 acc[4][4];
#pragma unroll
  for (int i = 0; i < 4; ++i)
#pragma unroll
    for (int j = 0; j < 4; ++j) acc[i][j] = (f32x4){0.f, 0.f, 0.f, 0.f};

  for (int k0 = 0; k0 < K; k0 += 32) {
#pragma unroll
    for (int r = 0; r < 2; ++r) {
      int rowe = r * 64 + (tid >> 2);
      const bf16_t* ga = Abase + (size_t)rowe * K + k0 + kc * 8;
      const bf16_t* gb = Bbase + (size_t)rowe * K + k0 + kc * 8;
      gload_lds16(ga, As + (size_t)(r * 256 + wave * 64) * 8);
      gload_lds16(gb, Bs + (size_t)(r * 256 + wave * 64) * 8);
    }
    __syncthreads();
    int kg = lane >> 4, lr = lane & 15;
    bf16x8 af[4], bfv[4];
#pragma unroll
    for (int i = 0; i < 4; ++i) {
      af[i]  = *(const bf16x8*)(As + ((wm * 64 + i * 16 + lr) * 32 + kg * 8));
      bfv[i] = *(const bf16x8*)(Bs + ((wn * 64 + i * 16 + lr) * 32 + kg * 8));
    }
#pragma unroll
    for (int i = 0; i < 4; ++i)
#pragma unroll
      for (int j = 0; j < 4; ++j)
        acc[i][j] = __builtin_amdgcn_mfma_f32_16x16x32_bf16(af[i], bfv[j], acc[i][j], 0, 0, 0);
    __syncthreads();
  }

#pragma unroll
  for (int i = 0; i < 4; ++i) {
    int r0 = by * 128 + wm * 64 + i * 16 + ((lane >> 4) << 2);
#pragma unroll
    for (int j = 0; j < 4; ++j) {
      int c = bx * 128 + wn * 64 + j * 16 + (lane & 15);
      float* Cp = C + (size_t)r0 * N + c;
#pragma unroll
      for (int q = 0; q < 4; ++q) Cp[(size_t)q * N] = acc[i][j][q];
    }
  }
}

// ---------- beta / g ----------
__global__ __launch_bounds__(64)
void k_ab(const float* __restrict__ hidden, const float* __restrict__ Wa,
          const float* __restrict__ Wb, const float* __restrict__ A_log,
          const float* __restrict__ dt_bias, float* __restrict__ g_out,
          float* __restrict__ beta_out) {
  int row = blockIdx.x;
  int lane = threadIdx.x;
  float accA[6] = {0, 0, 0, 0, 0, 0};
  float accB[6] = {0, 0, 0, 0, 0, 0};
  const float* h = hidden + (size_t)row * CC;
  for (int c = lane; c < CC; c += 64) {
    float x = h[c];
    const float* wa = Wa + c * 6;
    const float* wb = Wb + c * 6;
#pragma unroll
    for (int j = 0; j < 6; ++j) {
      accA[j] += x * wa[j];
      accB[j] += x * wb[j];
    }
  }
#pragma unroll
  for (int j = 0; j < 6; ++j) {
    for (int off = 32; off; off >>= 1) {
      accA[j] += __shfl_down(accA[j], off);
      accB[j] += __shfl_down(accB[j], off);
    }
  }
  if (lane == 0) {
#pragma unroll
    for (int j = 0; j < 6; ++j) {
      float a = accA[j] + dt_bias[j];
      float sp = (a > 20.f) ? a : log1pf(expf(a));
      g_out[(size_t)row * 6 + j] = -expf(A_log[j]) * sp;
      beta_out[(size_t)row * 6 + j] = 1.f / (1.f + expf(-accB[j]));
    }
  }
}

// ---------- depthwise causal conv(4) + SiLU (+ optional L2 norm); optional f32/bf16 outs ----------
__global__ void k_conv_silu(const float* __restrict__ pre, int ldpre, int col0,
                            const float* __restrict__ w, float* __restrict__ out,
                            bf16_t* __restrict__ out16, int ld_out, int do_norm) {
  int row = blockIdx.x;     // b*T + t
  int t = row & (TT - 1);
  int h = blockIdx.y;
  int kk = threadIdx.x;
  int perH = blockDim.x;
  int ch = h * perH + kk;
  const float* wp = w + ch * 4;
  float y = 0.f;
#pragma unroll
  for (int i = 0; i < 4; ++i) {
    int tt = t - 3 + i;
    if (tt >= 0) y += wp[i] * pre[(size_t)(row - 3 + i) * ldpre + col0 + ch];
  }
  float s = y / (1.f + expf(-y));
  if (do_norm) {
    float ss = s * s;
#pragma unroll
    for (int off = 32; off; off >>= 1) ss += __shfl_down(ss, off);
    __shared__ float red[2];
    if ((threadIdx.x & 63) == 0) red[threadIdx.x >> 6] = ss;
    __syncthreads();
    float nrm = sqrtf(red[0] + red[1]);
    s = s / (nrm + 1e-6f);
  }
  if (out) out[(size_t)row * ld_out + ch] = s;
  if (out16) out16[(size_t)row * ld_out + ch] = (bf16_t)s;
}

// ============ chunked gated delta rule ============
// Pass 1 (rewritten): M via MFMA from kb16; substitution columns in VGPRs.
// Dv in-place over vn; -W -> Wn16 (bf16 [t][k]); khatT -> khatT16 (bf16 [k][t]); cumsum -> bcum.
__global__ __launch_bounds__(384, 2)
void k_chunk1(const bf16_t* __restrict__ kb16, float* dv,
              const float* __restrict__ gdec, const float* __restrict__ beta,
              bf16_t* __restrict__ Wn16, bf16_t* __restrict__ khatT16,
              float* __restrict__ bcum) {
  __shared__ __align__(16) bf16_t ksh[64 * 128];   // [t][k], XOR-swizzled (16B slots)
  __shared__ __align__(16) float Ms[64 * 64];      // zeros at/above diagonal
  __shared__ float bc[64], bet[64];

  int tid = threadIdx.x;
  int bh = blockIdx.y, c = blockIdx.x;
  int b = bh / HH, h = bh % HH;
  int r0 = b * TT + c * CL;
  size_t cb = (size_t)bh * NC + c;
  int wq = tid >> 6, l = tid & 63;
  int lr = l & 15, lg = l >> 4;

  // stage k chunk (1024 16B slots), pre-XOR'd source -> swizzled LDS
#pragma unroll
  for (int it = 0; it < 3; ++it) {
    int idx = it * 384 + tid;
    if (idx < 1024) {
      int t = idx >> 4, p = idx & 15;
      int kslot = p ^ (t & 7);
      gload_lds16(kb16 + (size_t)(r0 + t) * KD + h * KK + kslot * 8,
                  ksh + (size_t)(it * 384 + wq * 64) * 8);
    }
  }
  // g cumsum + beta on wave 0
  if (tid < 64) {
    float val = gdec[(size_t)(r0 + tid) * HH + h];
    bet[tid] = beta[(size_t)(r0 + tid) * HH + h];
#pragma unroll
    for (int off = 1; off < 64; off <<= 1) {
      float o = __shfl_up(val, off, 64);
      if (tid >= off) val += o;
    }
    bc[tid] = val;
    bcum[cb * CL + tid] = val;
  }
  __syncthreads();
  float bL = bc[63];

  float rcol[64];
  if (wq < 4) {
    // M = mask(K K^T) * beta_t e^{b_t-b_s} via MFMA; wave wq owns t rows wq*16..+15
    f32x4 pacc[4];
#pragma unroll
    for (int sf = 0; sf < 4; ++sf) pacc[sf] = (f32x4){0.f, 0.f, 0.f, 0.f};
#pragma unroll
    for (int ks_ = 0; ks_ < 4; ++ks_) {
      int trow = wq * 16 + lr;
      bf16x8 aK = *(const bf16x8*)((const char*)ksh + trow * 256 + (((ks_ * 4 + lg) * 16) ^ ((trow & 7) << 4)));
#pragma unroll
      for (int sf = 0; sf < 4; ++sf) {
        int srow = sf * 16 + lr;
        bf16x8 bK = *(const bf16x8*)((const char*)ksh + srow * 256 + (((ks_ * 4 + lg) * 16) ^ ((srow & 7) << 4)));
        pacc[sf] = __builtin_amdgcn_mfma_f32_16x16x32_bf16(aK, bK, pacc[sf], 0, 0, 0);
      }
    }
#pragma unroll
    for (int sf = 0; sf < 4; ++sf)
#pragma unroll
      for (int q = 0; q < 4; ++q) {
        int t = wq * 16 + lg * 4 + q;
        int s = sf * 16 + lr;
        Ms[t * 64 + s] = (s < t) ? bet[t] * __expf(bc[t] - bc[s]) * pacc[sf][q] : 0.f;
      }
    // RHS for v-column col = tid (0..255)
    const float* dvc = dv + (size_t)r0 * VD + h * VV + tid;
#pragma unroll
    for (int t = 0; t < 64; ++t) rcol[t] = dvc[(size_t)t * VD];
#pragma unroll
    for (int t = 0; t < 64; ++t) rcol[t] *= bet[t];
  } else {
    // waves 4,5: khatT16 production + k-column RHS (col-256 = kk)
    int kk = (wq - 4) * 64 + l;
    bf16_t* kout = khatT16 + cb * (size_t)(KK * CL) + (size_t)kk * CL;
#pragma unroll
    for (int t8 = 0; t8 < 8; ++t8) {
      union { bf16x8 v; bf16_t e[8]; } u;
#pragma unroll
      for (int e = 0; e < 8; ++e) {
        int t = t8 * 8 + e;
        float kval = (float)*(const bf16_t*)((const char*)ksh + t * 256 +
                        ((((kk >> 3) ^ (t & 7)) * 16) + (kk & 7) * 2));
        u.e[e] = (bf16_t)(__expf(bL - bc[t]) * kval);
        rcol[t] = bet[t] * __expf(bc[t]) * kval;
      }
      *(bf16x8*)(kout + t8 * 8) = u.v;
    }
  }
  __syncthreads();

  // forward substitution, column in registers; zeros above diag make tails uniform
#pragma unroll
  for (int t = 1; t < 64; ++t) {
    const f32x4* row = (const f32x4*)&Ms[t * 64];
    float a0 = 0.f, a1 = 0.f, a2 = 0.f, a3 = 0.f;
    const int n4 = (t + 3) >> 2;
#pragma unroll
    for (int s4 = 0; s4 < n4; ++s4) {
      f32x4 m = row[s4];
      a0 += m[0] * rcol[s4 * 4 + 0];
      a1 += m[1] * rcol[s4 * 4 + 1];
      a2 += m[2] * rcol[s4 * 4 + 2];
      a3 += m[3] * rcol[s4 * 4 + 3];
    }
    rcol[t] -= (a0 + a1) + (a2 + a3);
  }

  // write out
  if (wq < 4) {
    float* dvc = dv + (size_t)r0 * VD + h * VV + tid;
#pragma unroll
    for (int t = 0; t < 64; ++t) dvc[(size_t)t * VD] = rcol[t];
  } else {
    int kk = (wq - 4) * 64 + l;
#pragma unroll
    for (int t = 0; t < 64; ++t)
      Wn16[(cb * CL + t) * KK + kk] = (bf16_t)(-rcol[t]);
  }
}

// Pass 2: MFMA state propagation. Grid (8 vtiles of 32, 12 bh), 256 thr (4 waves).
// S (f32) lives in accumulators across all 16 chunks (k-split across waves).
// Emits chunk-start states S0^T (bf16 [v][k]) and Zt (bf16 [v][t]).
__global__ __launch_bounds__(256, 1)
void k_chunk2(const float* __restrict__ dv, const bf16_t* __restrict__ Wn16,
              const bf16_t* __restrict__ khatT16, const float* __restrict__ bcum,
              bf16_t* __restrict__ states, bf16_t* __restrict__ Zt) {
  __shared__ __align__(16) bf16_t St[32 * 128];   // [v][k], XOR-swizzled
  __shared__ __align__(16) bf16_t Zl[32 * 64];    // [v][t], XOR-swizzled
  int tid = threadIdx.x;
  int vt = blockIdx.x, bh = blockIdx.y;
  int b = bh / HH, h = bh % HH;
  int wq = tid >> 6, l = tid & 63;
  int lr = l & 15, lg = l >> 4;

  f32x4 acc[2][2];
#pragma unroll
  for (int kf = 0; kf < 2; ++kf)
#pragma unroll
    for (int vf = 0; vf < 2; ++vf) acc[kf][vf] = (f32x4){0.f, 0.f, 0.f, 0.f};

  for (int c = 0; c < NC; ++c) {
    size_t cb = (size_t)bh * NC + c;
    int r0 = b * TT + c * CL;
    float ebL = __expf(bcum[cb * CL + 63]);

    // A: S acc -> St bf16 (swizzled)
#pragma unroll
    for (int kf = 0; kf < 2; ++kf)
#pragma unroll
      for (int vf = 0; vf < 2; ++vf)
#pragma unroll
        for (int q = 0; q < 4; ++q) {
          int k = wq * 32 + kf * 16 + lg * 4 + q;
          int v = vf * 16 + lr;
          *(bf16_t*)((char*)St + v * 256 + ((k * 2) ^ ((v & 7) << 4))) = (bf16_t)acc[kf][vf][q];
        }
    __syncthreads();

    // B: states copy (S0^T for pass 3)
#pragma unroll
    for (int it = 0; it < 2; ++it) {
      int idx = tid + it * 256;
      int v = idx >> 4, slot = idx & 15;
      bf16x8 val = *(const bf16x8*)((const char*)St + v * 256 + ((slot * 16) ^ ((v & 7) << 4)));
      *(bf16x8*)(states + ((size_t)cb * 256 + vt * 32 + v) * 128 + slot * 8) = val;
    }

    // Z = Dv + (-W) * S  : per wave 16t x 32v
    f32x4 zacc[2];
#pragma unroll
    for (int vf = 0; vf < 2; ++vf)
#pragma unroll
      for (int q = 0; q < 4; ++q) {
        int t = wq * 16 + lg * 4 + q;
        zacc[vf][q] = dv[(size_t)(r0 + t) * VD + h * VV + vt * 32 + vf * 16 + lr];
      }
#pragma unroll
    for (int ks_ = 0; ks_ < 4; ++ks_) {
      bf16x8 aW = *(const bf16x8*)(Wn16 + (cb * CL + wq * 16 + lr) * KK + ks_ * 32 + lg * 8);
#pragma unroll
      for (int vf = 0; vf < 2; ++vf) {
        int v = vf * 16 + lr;
        bf16x8 bS = *(const bf16x8*)((const char*)St + v * 256 + (((ks_ * 32 + lg * 8) * 2) ^ ((v & 7) << 4)));
        zacc[vf] = __builtin_amdgcn_mfma_f32_16x16x32_bf16(aW, bS, zacc[vf], 0, 0, 0);
      }
    }
    // Zl write (bf16 [v][t] swizzled)
#pragma unroll
    for (int vf = 0; vf < 2; ++vf)
#pragma unroll
      for (int q = 0; q < 4; ++q) {
        int t = wq * 16 + lg * 4 + q;
        int v = vf * 16 + lr;
        *(bf16_t*)((char*)Zl + v * 128 + ((t * 2) ^ ((v & 7) << 4))) = (bf16_t)zacc[vf][q];
      }
    __syncthreads();

    // D: Zt copy to global
    {
      int v = tid >> 3, slot = tid & 7;
      bf16x8 val = *(const bf16x8*)((const char*)Zl + v * 128 + ((slot * 16) ^ ((v & 7) << 4)));
      *(bf16x8*)(Zt + ((size_t)cb * 256 + vt * 32 + v) * 64 + slot * 8) = val;
    }
    // S decay + S += khatT * Z
#pragma unroll
    for (int kf = 0; kf < 2; ++kf)
#pragma unroll
      for (int vf = 0; vf < 2; ++vf)
#pragma unroll
        for (int q = 0; q < 4; ++q) acc[kf][vf][q] *= ebL;
#pragma unroll
    for (int ts = 0; ts < 2; ++ts) {
      bf16x8 aK[2], bZ[2];
#pragma unroll
      for (int kf = 0; kf < 2; ++kf)
        aK[kf] = *(const bf16x8*)(khatT16 + (cb * KK + wq * 32 + kf * 16 + lr) * CL + ts * 32 + lg * 8);
#pragma unroll
      for (int vf = 0; vf < 2; ++vf) {
        int v = vf * 16 + lr;
        bZ[vf] = *(const bf16x8*)((const char*)Zl + v * 128 + (((ts * 32 + lg * 8) * 2) ^ ((v & 7) << 4)));
      }
#pragma unroll
      for (int kf = 0; kf < 2; ++kf)
#pragma unroll
        for (int vf = 0; vf < 2; ++vf)
          acc[kf][vf] = __builtin_amdgcn_mfma_f32_16x16x32_bf16(aK[kf], bZ[vf], acc[kf][vf], 0, 0, 0);
    }
  }
}

// Pass 3: o = e^{b_t} q^T S0 + P Z, all MFMA. Grid (NC, 12), 256 thr.
__global__ __launch_bounds__(256, 1)
void k_chunk3(const bf16_t* __restrict__ qb16, const bf16_t* __restrict__ kb16,
              const bf16_t* __restrict__ Zt, const bf16_t* __restrict__ states,
              const float* __restrict__ bcum, float* __restrict__ attn) {
  __shared__ __align__(16) bf16_t qs[64 * 128];   // [t][k] swizzled via pre-XOR source
  __shared__ __align__(16) bf16_t ksh[64 * 128];
  __shared__ __align__(16) bf16_t Pl[64 * 64];    // [t][s] swizzled
  __shared__ float bcs[64];

  int tid = threadIdx.x;
  int c = blockIdx.x, bh = blockIdx.y;
  int b = bh / HH, h = bh % HH;
  int r0 = b * TT + c * CL;
  size_t cb = (size_t)bh * NC + c;
  int wq = tid >> 6, l = tid & 63;
  int lr = l & 15, lg = l >> 4;

  if (tid < 64) bcs[tid] = bcum[cb * CL + tid];
#pragma unroll
  for (int it = 0; it < 4; ++it) {
    int idx = it * 256 + tid;
    int t = idx >> 4, p = idx & 15;
    int kslot = p ^ (t & 7);
    gload_lds16(qb16 + (size_t)(r0 + t) * KD + h * KK + kslot * 8,
                qs + (size_t)(it * 256 + wq * 64) * 8);
    gload_lds16(kb16 + (size_t)(r0 + t) * KD + h * KK + kslot * 8,
                ksh + (size_t)(it * 256 + wq * 64) * 8);
  }
  __syncthreads();

  // P = mask(q k^T) * e^{b_t-b_s}; wave wq covers t rows wq*16..+15
  f32x4 pacc[4];
#pragma unroll
  for (int sf = 0; sf < 4; ++sf) pacc[sf] = (f32x4){0.f, 0.f, 0.f, 0.f};
#pragma unroll
  for (int ks_ = 0; ks_ < 4; ++ks_) {
    int trow = wq * 16 + lr;
    bf16x8 aQ = *(const bf16x8*)((const char*)qs + trow * 256 + (((ks_ * 4 + lg) * 16) ^ ((trow & 7) << 4)));
#pragma unroll
    for (int sf = 0; sf < 4; ++sf) {
      int srow = sf * 16 + lr;
      bf16x8 bK = *(const bf16x8*)((const char*)ksh + srow * 256 + (((ks_ * 4 + lg) * 16) ^ ((srow & 7) << 4)));
      pacc[sf] = __builtin_amdgcn_mfma_f32_16x16x32_bf16(aQ, bK, pacc[sf], 0, 0, 0);
    }
  }
#pragma unroll
  for (int sf = 0; sf < 4; ++sf)
#pragma unroll
    for (int q = 0; q < 4; ++q) {
      int t = wq * 16 + lg * 4 + q;
      int s = sf * 16 + lr;
      float val = (s <= t) ? pacc[sf][q] * __expf(bcs[t] - bcs[s]) : 0.f;
      *(bf16_t*)((char*)Pl + t * 128 + ((s * 2) ^ ((t & 7) << 4))) = (bf16_t)val;
    }
  __syncthreads();

  // O: wave wq covers v cols wq*64..+63; oacc = qhat*S0^T + P*Zt
  f32x4 oacc[4][4];
#pragma unroll
  for (int ti = 0; ti < 4; ++ti)
#pragma unroll
    for (int vj = 0; vj < 4; ++vj) oacc[ti][vj] = (f32x4){0.f, 0.f, 0.f, 0.f};

#pragma unroll
  for (int ks_ = 0; ks_ < 4; ++ks_) {
    bf16x8 aQ[4];
#pragma unroll
    for (int ti = 0; ti < 4; ++ti) {
      int t = ti * 16 + lr;
      union { bf16x8 v; bf16_t e[8]; } u;
      u.v = *(const bf16x8*)((const char*)qs + t * 256 + (((ks_ * 4 + lg) * 16) ^ ((t & 7) << 4)));
      float eb = __expf(bcs[t]);
#pragma unroll
      for (int e = 0; e < 8; ++e) u.e[e] = (bf16_t)((float)u.e[e] * eb);
      aQ[ti] = u.v;
    }
#pragma unroll
    for (int vj = 0; vj < 4; ++vj) {
      int vrow = wq * 64 + vj * 16 + lr;
      bf16x8 bS = *(const bf16x8*)(states + ((size_t)cb * 256 + vrow) * 128 + ks_ * 32 + lg * 8);
#pragma unroll
      for (int ti = 0; ti < 4; ++ti)
        oacc[ti][vj] = __builtin_amdgcn_mfma_f32_16x16x32_bf16(aQ[ti], bS, oacc[ti][vj], 0, 0, 0);
    }
  }
#pragma unroll
  for (int ts = 0; ts < 2; ++ts) {
    bf16x8 aP[4];
#pragma unroll
    for (int ti = 0; ti < 4; ++ti) {
      int t = ti * 16 + lr;
      aP[ti] = *(const bf16x8*)((const char*)Pl + t * 128 + (((ts * 4 + lg) * 16) ^ ((t & 7) << 4)));
    }
#pragma unroll
    for (int vj = 0; vj < 4; ++vj) {
      int vrow = wq * 64 + vj * 16 + lr;
      bf16x8 bZ = *(const bf16x8*)(Zt + ((size_t)cb * 256 + vrow) * 64 + ts * 32 + lg * 8);
#pragma unroll
      for (int ti = 0; ti < 4; ++ti)
        oacc[ti][vj] = __builtin_amdgcn_mfma_f32_16x16x32_bf16(aP[ti], bZ, oacc[ti][vj], 0, 0, 0);
    }
  }
#pragma unroll
  for (int ti = 0; ti < 4; ++ti)
#pragma unroll
    for (int vj = 0; vj < 4; ++vj)
#pragma unroll
      for (int q = 0; q < 4; ++q) {
        int t = ti * 16 + lg * 4 + q;
        int v = wq * 64 + vj * 16 + lr;
        attn[(size_t)(r0 + t) * VD + h * VV + v] = oacc[ti][vj][q];
      }
}

// ---------- gated RMSNorm + cast to bf16 ----------
__global__ __launch_bounds__(256)
void k_gatenorm(const float* __restrict__ attn, const float* __restrict__ fgate,
                const float* __restrict__ onorm_w, bf16_t* __restrict__ out) {
  int row = blockIdx.x;
  int h = blockIdx.y;
  int vi = threadIdx.x;
  float x = attn[(size_t)row * VD + h * VV + vi];
  float ss = x * x;
#pragma unroll
  for (int off = 32; off; off >>= 1) ss += __shfl_down(ss, off);
  __shared__ float red[4];
  if ((threadIdx.x & 63) == 0) red[threadIdx.x >> 6] = ss;
  __syncthreads();
  float tot = red[0] + red[1] + red[2] + red[3];
  float r = rsqrtf(tot / (float)VV + 1e-5f);
  float gate = fgate[(size_t)row * VD + h * VV + vi];
  float y = x * r * onorm_w[vi] * (gate / (1.f + expf(-gate)));
  out[(size_t)row * VD + h * VV + vi] = (bf16_t)y;
}

extern "C" void kernel_launch(void* const* d_in, const int* in_sizes, int n_in,
                              void* d_out, int out_size, void* d_ws, size_t ws_size,
                              hipStream_t stream) {
  const float* hidden = (const float*)d_in[0];
  const float* Wq = (const float*)d_in[1];
  const float* Wk = (const float*)d_in[2];
  const float* Wv = (const float*)d_in[3];
  const float* Wa = (const float*)d_in[4];
  const float* Wb = (const float*)d_in[5];
  const float* A_log = (const float*)d_in[6];
  const float* dt_bias = (const float*)d_in[7];
  const float* qconv = (const float*)d_in[8];
  const float* kconv = (const float*)d_in[9];
  const float* vconv = (const float*)d_in[10];
  const float* Wg = (const float*)d_in[11];
  const float* onorm = (const float*)d_in[12];
  const float* Wo = (const float*)d_in[13];
  float* out = (float*)d_out;

  char* ws = (char*)d_ws;
  size_t off = 0;
  auto alloc = [&](size_t bytes) {
    void* p = ws + off;
    off += (bytes + 255) & ~(size_t)255;
    return p;
  };
  const int M = BB * TT;  // 2048
  bf16_t* hbf   = (bf16_t*)alloc((size_t)M * CC * 2);       // aliased by Wn16/khatT16 later
  bf16_t* WcatT = (bf16_t*)alloc((size_t)NCAT * CC * 2);
  bf16_t* WoT   = (bf16_t*)alloc((size_t)CC * VD * 2);
  float*  fqkv  = (float*) alloc((size_t)M * NQKV * 4);     // aliased by states+attn later
  float*  fgate = (float*) alloc((size_t)M * VD * 4);
  float*  kn    = (float*) alloc((size_t)M * KD * 4);       // aliased by Zt later
  float*  vn    = (float*) alloc((size_t)M * VD * 4);       // becomes Dv in pass 1
  float*  gdec  = (float*) alloc((size_t)M * HH * 4);
  float*  beta  = (float*) alloc((size_t)M * HH * 4);
  bf16_t* ovd   = (bf16_t*)alloc((size_t)M * VD * 2);
  bf16_t* qb16  = (bf16_t*)alloc((size_t)M * KD * 2);
  bf16_t* kb16  = (bf16_t*)alloc((size_t)M * KD * 2);
  float*  bcum  = (float*) alloc((size_t)12 * NC * CL * 4);

  // aliases (stream-ordered lifetime separation):
  bf16_t* Wn16    = (bf16_t*)hbf;                    // 12*16*64*128 bf16 = 3.15MB
  bf16_t* khatT16 = Wn16 + (size_t)12 * NC * CL * KK; // +3.15MB (hbf is 8.4MB)
  bf16_t* states  = (bf16_t*)fqkv;                   // 12*16*256*128 bf16 = 12.6MB
  float*  attn    = (float*)((char*)fqkv + (size_t)12 * NC * VV * KK * 2);
  bf16_t* Zt      = (bf16_t*)kn;                     // 12*16*256*64 bf16 = 6.3MB

  // pre-pass
  k_cvt_bf16<<<(M * CC / 4 + 255) / 256, 256, 0, stream>>>(hidden, hbf, M * CC);
  k_transpose_cvt<<<dim3(KD / 32, CC / 32), dim3(32, 8), 0, stream>>>(Wq, WcatT, CC, KD);
  k_transpose_cvt<<<dim3(KD / 32, CC / 32), dim3(32, 8), 0, stream>>>(Wk, WcatT + (size_t)768 * CC, CC, KD);
  k_transpose_cvt<<<dim3(VD / 32, CC / 32), dim3(32, 8), 0, stream>>>(Wv, WcatT + (size_t)1536 * CC, CC, VD);
  k_transpose_cvt<<<dim3(VD / 32, CC / 32), dim3(32, 8), 0, stream>>>(Wg, WcatT + (size_t)3072 * CC, CC, VD);
  k_transpose_cvt<<<dim3(CC / 32, VD / 32), dim3(32, 8), 0, stream>>>(Wo, WoT, VD, CC);

  // projections
  k_gemm_bt<<<dim3(NQKV / 128, M / 128), 256, 0, stream>>>(hbf, WcatT, fqkv, M, NQKV, CC);
  k_gemm_bt<<<dim3(VD / 128, M / 128), 256, 0, stream>>>(hbf, WcatT + (size_t)3072 * CC, fgate, M, VD, CC);

  // beta / g
  k_ab<<<M, 64, 0, stream>>>(hidden, Wa, Wb, A_log, dt_bias, gdec, beta);

  // conv + silu (+norm for q,k)
  k_conv_silu<<<dim3(M, HH), 128, 0, stream>>>(fqkv, NQKV, 0, qconv, nullptr, qb16, KD, 1);
  k_conv_silu<<<dim3(M, HH), 128, 0, stream>>>(fqkv, NQKV, 768, kconv, nullptr, kb16, KD, 1);
  k_conv_silu<<<dim3(M, HH), 256, 0, stream>>>(fqkv, NQKV, 1536, vconv, vn, nullptr, VD, 0);

  // chunked gated delta rule (hbf dead -> Wn16/khatT16; fqkv dead -> states/attn; kn dead -> Zt)
  k_chunk1<<<dim3(NC, 12), 384, 0, stream>>>(kb16, vn, gdec, beta, Wn16, khatT16, bcum);
  k_chunk2<<<dim3(8, 12), 256, 0, stream>>>(vn, Wn16, khatT16, bcum, states, Zt);
  k_chunk3<<<dim3(NC, 12), 256, 0, stream>>>(qb16, kb16, Zt, states, bcum, attn);

  // gated RMSNorm -> bf16
  k_gatenorm<<<dim3(M, HH), 256, 0, stream>>>(attn, fgate, onorm, ovd);

  // output projection
  k_gemm_bt<<<dim3(CC / 128, M / 128), 256, 0, stream>>>(ovd, WoT, out, M, CC, VD);
}